// Round 7
// baseline (858.023 us; speedup 1.0000x reference)
//
#include <hip/hip_runtime.h>
#include <hip/hip_fp16.h>
#include <math.h>

// ---------------------------------------------------------------- CSR build
__global__ __launch_bounds__(256) void count_kernel(const int* __restrict__ dst,
                                                    int* __restrict__ deg, int E) {
    int e = blockIdx.x * 256 + threadIdx.x;
    if (e < E) atomicAdd(&deg[dst[e]], 1);
}

#define SCAN_TPB 256
#define SCAN_VPT 4
#define SCAN_ELEMS (SCAN_TPB * SCAN_VPT)  // 1024

__global__ __launch_bounds__(256) void scan_phase1(const int* __restrict__ deg,
                                                   int* __restrict__ bsum, int n) {
    __shared__ int sh[SCAN_TPB];
    int base = blockIdx.x * SCAN_ELEMS + threadIdx.x * SCAN_VPT;
    int s = 0;
#pragma unroll
    for (int j = 0; j < SCAN_VPT; j++) { int i = base + j; if (i < n) s += deg[i]; }
    sh[threadIdx.x] = s;
    __syncthreads();
    for (int off = 128; off; off >>= 1) {
        if (threadIdx.x < (unsigned)off) sh[threadIdx.x] += sh[threadIdx.x + off];
        __syncthreads();
    }
    if (threadIdx.x == 0) bsum[blockIdx.x] = sh[0];
}

__global__ __launch_bounds__(256) void scan_phase2(int* __restrict__ bsum, int nb,
                                                   int* __restrict__ rowptr, int n) {
    __shared__ int sh[256];
    int v = (threadIdx.x < (unsigned)nb) ? bsum[threadIdx.x] : 0;
    sh[threadIdx.x] = v;
    __syncthreads();
    for (int off = 1; off < 256; off <<= 1) {
        int t = (threadIdx.x >= (unsigned)off) ? sh[threadIdx.x - off] : 0;
        __syncthreads();
        sh[threadIdx.x] += t;
        __syncthreads();
    }
    if (threadIdx.x < (unsigned)nb) bsum[threadIdx.x] = sh[threadIdx.x] - v;  // exclusive
    if (threadIdx.x == 0) rowptr[n] = sh[255];                                // total
}

__global__ __launch_bounds__(256) void scan_phase3(const int* __restrict__ deg,
                                                   const int* __restrict__ bsum,
                                                   int* __restrict__ rowptr,
                                                   int* __restrict__ cursor, int n) {
    __shared__ int sh[SCAN_TPB];
    int tid = threadIdx.x;
    int base = blockIdx.x * SCAN_ELEMS + tid * SCAN_VPT;
    int v[SCAN_VPT];
    int s = 0;
#pragma unroll
    for (int j = 0; j < SCAN_VPT; j++) { int i = base + j; v[j] = (i < n) ? deg[i] : 0; s += v[j]; }
    sh[tid] = s;
    __syncthreads();
    for (int off = 1; off < SCAN_TPB; off <<= 1) {
        int t = (tid >= off) ? sh[tid - off] : 0;
        __syncthreads();
        sh[tid] += t;
        __syncthreads();
    }
    int ex = sh[tid] - s + bsum[blockIdx.x];
#pragma unroll
    for (int j = 0; j < SCAN_VPT; j++) {
        int i = base + j;
        if (i < n) { rowptr[i] = ex; cursor[i] = ex; ex += v[j]; }
    }
}

// CSR record: {src_as_float_bits, ea0, ea1, ea2} — one s_load_dwordx4 per edge
__global__ __launch_bounds__(256) void scatter_kernel(const int* __restrict__ src,
                                                      const int* __restrict__ dst,
                                                      const float* __restrict__ ea,
                                                      int* __restrict__ cursor,
                                                      float4* __restrict__ csr4, int E) {
    int e = blockIdx.x * 256 + threadIdx.x;
    if (e < E) {
        int d = dst[e];
        int pos = atomicAdd(&cursor[d], 1);
        size_t eb3 = (size_t)e * 3;
        csr4[pos] = make_float4(__int_as_float(src[e]), ea[eb3], ea[eb3 + 1], ea[eb3 + 2]);
    }
}

// ------------- epilogue constants: A = 0.25*g*rsqrt(v+eps); B = (bias-m)*s+b
__global__ __launch_bounds__(256) void bnprep_kernel(const float* __restrict__ c0,
                                                     const float* __restrict__ cb,   // [3][64]
                                                     const float* __restrict__ bng,
                                                     const float* __restrict__ bnb,
                                                     const float* __restrict__ bnm,
                                                     const float* __restrict__ bnv,
                                                     float* __restrict__ epi) {      // [4][2][64]
    int t = threadIdx.x;           // exactly 256 = 4 layers x 64 channels
    int l = t >> 6, c = t & 63;
    float s = bng[l * 64 + c] * rsqrtf(bnv[l * 64 + c] + 1e-5f);
    float bias = (l == 0) ? c0[c] : cb[(l - 1) * 64 + c];
    epi[l * 128 + c] = 0.25f * s;
    epi[l * 128 + 64 + c] = (bias - bnm[l * 64 + c]) * s + bnb[l * 64 + c];
}

// --------------------- xl = fp16(x@Wl+bl) [gather payload], xr = x@Wr (fp32)
#define GROWS 32
__global__ __launch_bounds__(256) void gemm2_kernel(const float* __restrict__ xin, int K,
                                                    const float* __restrict__ Wl,
                                                    const float* __restrict__ bl,
                                                    const float* __restrict__ Wr,
                                                    __half* __restrict__ xl,
                                                    float* __restrict__ xr, int Nn) {
    __shared__ __align__(16) float sh[GROWS][64];
    int j = threadIdx.x;  // output column 0..255
    int n0 = blockIdx.x * GROWS;
    for (int t = threadIdx.x; t < GROWS * K; t += 256) {
        int r = t / K, k = t - r * K;
        int n = n0 + r;
        sh[r][k] = (n < Nn) ? xin[(size_t)n * K + k] : 0.f;
    }
    __syncthreads();
    float accl[GROWS], accr[GROWS];
    float b = bl[j];
#pragma unroll
    for (int r = 0; r < GROWS; r++) { accl[r] = b; accr[r] = 0.f; }
    if (K == 64) {
        for (int k4 = 0; k4 < 16; k4++) {
            int k = k4 * 4;
            float wl0 = Wl[(k + 0) * 256 + j], wl1 = Wl[(k + 1) * 256 + j];
            float wl2 = Wl[(k + 2) * 256 + j], wl3 = Wl[(k + 3) * 256 + j];
            float wr0 = Wr[(k + 0) * 256 + j], wr1 = Wr[(k + 1) * 256 + j];
            float wr2 = Wr[(k + 2) * 256 + j], wr3 = Wr[(k + 3) * 256 + j];
#pragma unroll
            for (int r = 0; r < GROWS; r++) {
                float4 h4 = *(const float4*)&sh[r][k];
                accl[r] += h4.x * wl0 + h4.y * wl1 + h4.z * wl2 + h4.w * wl3;
                accr[r] += h4.x * wr0 + h4.y * wr1 + h4.z * wr2 + h4.w * wr3;
            }
        }
    } else {
        for (int k = 0; k < K; k++) {
            float wl = Wl[k * 256 + j], wr = Wr[k * 256 + j];
#pragma unroll
            for (int r = 0; r < GROWS; r++) { accl[r] += sh[r][k] * wl; accr[r] += sh[r][k] * wr; }
        }
    }
    for (int r = 0; r < GROWS; r++) {
        int n = n0 + r;
        if (n < Nn) {
            xl[(size_t)n * 256 + j] = __float2half_rn(accl[r]);
            xr[(size_t)n * 256 + j] = accr[r];
        }
    }
}

// --------------------------- fused GATv2: persistent wave, TWO interleaved
// node-chains per wave (A = d, B = d+nwaves). Each chain: issue (scalar csr4
// loads + 8 fp16 row gathers) separated from compute, interleaved
// issueA/issueB/computeA/re-issueA/computeB/re-issueB so each chain's gather
// latency hides under the other's work. Softmax with implicit C=0 (exact for
// this model's O(0.3) scores). Epilogue constants precomputed (bnprep).
#define EB 8

#define LOAD_META(S, dd)                                                                 \
    i0##S = 0; end##S = 0;                                                               \
    if ((dd) < Nn) {                                                                     \
        i0##S = __builtin_amdgcn_readfirstlane(rowptr[dd]);                              \
        end##S = __builtin_amdgcn_readfirstlane(rowptr[(dd) + 1]);                       \
        xrv##S = *(const float4*)&xr[((size_t)(dd) << 8) + (lane << 2)];                 \
        res##S = hres ? *(const float4*)&hres[((size_t)(dd) << 6) + ((lane & 15) << 2)]  \
                      : make_float4(0.f, 0.f, 0.f, 0.f);                                 \
        lr##S = 0.f;                                                                     \
        acc##S = make_float4(0.f, 0.f, 0.f, 0.f);                                        \
    }

#define ISSUE(S)                                                                         \
    if (i0##S < end##S) {                                                                \
        _Pragma("unroll") for (int j = 0; j < EB; j++) {                                 \
            int idx = i0##S + j;                                                         \
            if (idx < end##S) {                                                          \
                float4 ce = csr4[idx]; /* uniform -> s_load_dwordx4 */                   \
                cey##S[j] = ce.y; cez##S[j] = ce.z; cew##S[j] = ce.w;                    \
                int sn = __builtin_amdgcn_readfirstlane(__float_as_int(ce.x));           \
                xpk##S[j] = *(const uint2*)(xl + ((size_t)sn << 8) + (lane << 2));       \
            } else {                                                                     \
                xpk##S[j] = make_uint2(0u, 0u);                                          \
            }                                                                            \
        }                                                                                \
    }

#define COMPUTE(S)                                                                       \
    if (i0##S < end##S) {                                                                \
        float p[EB];                                                                     \
        _Pragma("unroll") for (int j = 0; j < EB; j++) {                                 \
            int idx = i0##S + j;                                                         \
            if (idx < end##S) {                                                          \
                float2 f0 = __half22float2(*(const __half2*)&xpk##S[j].x);               \
                float2 f1 = __half22float2(*(const __half2*)&xpk##S[j].y);               \
                float tx = fmaf(cey##S[j], we0.x,                                        \
                            fmaf(cez##S[j], we1.x, fmaf(cew##S[j], we2.x, xrv##S.x)))    \
                           + f0.x;                                                       \
                float ty = fmaf(cey##S[j], we0.y,                                        \
                            fmaf(cez##S[j], we1.y, fmaf(cew##S[j], we2.y, xrv##S.y)))    \
                           + f0.y;                                                       \
                float tz = fmaf(cey##S[j], we0.z,                                        \
                            fmaf(cez##S[j], we1.z, fmaf(cew##S[j], we2.z, xrv##S.z)))    \
                           + f1.x;                                                       \
                float tw = fmaf(cey##S[j], we0.w,                                        \
                            fmaf(cez##S[j], we1.w, fmaf(cew##S[j], we2.w, xrv##S.w)))    \
                           + f1.y;                                                       \
                float pp = tx * (tx > 0.f ? attv.x : att02.x);                           \
                pp = fmaf(ty, (ty > 0.f ? attv.y : att02.y), pp);                        \
                pp = fmaf(tz, (tz > 0.f ? attv.z : att02.z), pp);                        \
                pp = fmaf(tw, (tw > 0.f ? attv.w : att02.w), pp);                        \
                p[j] = pp;                                                               \
            } else p[j] = -INFINITY;                                                     \
        }                                                                                \
        _Pragma("unroll") for (int off = 1; off < 16; off <<= 1) {                       \
            _Pragma("unroll") for (int j = 0; j < EB; j++) p[j] += __shfl_xor(p[j], off);\
        }                                                                                \
        _Pragma("unroll") for (int j = 0; j < EB; j++) {                                 \
            float wv = __expf(p[j]);                                                     \
            float2 f0 = __half22float2(*(const __half2*)&xpk##S[j].x);                   \
            float2 f1 = __half22float2(*(const __half2*)&xpk##S[j].y);                   \
            acc##S.x = fmaf(wv, f0.x, acc##S.x);                                         \
            acc##S.y = fmaf(wv, f0.y, acc##S.y);                                         \
            acc##S.z = fmaf(wv, f1.x, acc##S.z);                                         \
            acc##S.w = fmaf(wv, f1.y, acc##S.w);                                         \
            lr##S += wv;                                                                 \
        }                                                                                \
        i0##S += EB;                                                                     \
    }

#define EPILOGUE(S, dd)                                                                  \
    {                                                                                    \
        float inv = (lr##S > 0.f) ? 1.f / lr##S : 0.f;                                   \
        float4 o = make_float4(acc##S.x * inv, acc##S.y * inv,                           \
                               acc##S.z * inv, acc##S.w * inv);                          \
        _Pragma("unroll") for (int off = 16; off < 64; off <<= 1) {                      \
            o.x += __shfl_xor(o.x, off);                                                 \
            o.y += __shfl_xor(o.y, off);                                                 \
            o.z += __shfl_xor(o.z, off);                                                 \
            o.w += __shfl_xor(o.w, off);                                                 \
        }                                                                                \
        if (lane < 16) {                                                                 \
            float vx = fmaf(o.x, eA.x, eB4.x);                                           \
            float vy = fmaf(o.y, eA.y, eB4.y);                                           \
            float vz = fmaf(o.z, eA.z, eB4.z);                                           \
            float vw = fmaf(o.w, eA.w, eB4.w);                                           \
            vx = vx > 0.f ? vx : expm1f(vx);                                             \
            vy = vy > 0.f ? vy : expm1f(vy);                                             \
            vz = vz > 0.f ? vz : expm1f(vz);                                             \
            vw = vw > 0.f ? vw : expm1f(vw);                                             \
            vx += res##S.x; vy += res##S.y; vz += res##S.z; vw += res##S.w;              \
            *(float4*)&hout[((size_t)(dd) << 6) + (lane << 2)] =                         \
                make_float4(vx, vy, vz, vw);                                             \
        }                                                                                \
    }

__global__ __launch_bounds__(256) void gat_kernel(const __half* __restrict__ xl,
                                                  const float* __restrict__ xr,
                                                  const float* __restrict__ We,   // [3,256]
                                                  const float* __restrict__ att,  // [256]
                                                  const float* __restrict__ epi,  // [2][64]
                                                  const int* __restrict__ rowptr,
                                                  const float4* __restrict__ csr4,
                                                  float* __restrict__ hout,       // [N,64]
                                                  const float* __restrict__ hres, // [N,64] or null
                                                  int Nn) {
    int tid = threadIdx.x;
    int w = tid >> 6, lane = tid & 63;
    int wave = blockIdx.x * 4 + w;
    int nwaves = gridDim.x * 4;

    float4 we0 = *(const float4*)&We[lane * 4];
    float4 we1 = *(const float4*)&We[256 + lane * 4];
    float4 we2 = *(const float4*)&We[512 + lane * 4];
    float4 attv = *(const float4*)&att[lane * 4];
    float4 att02 = make_float4(0.2f * attv.x, 0.2f * attv.y, 0.2f * attv.z, 0.2f * attv.w);
    float4 eA = *(const float4*)&epi[(lane & 15) * 4];
    float4 eB4 = *(const float4*)&epi[64 + (lane & 15) * 4];

    int i0A, endA, i0B, endB;
    float lrA = 0.f, lrB = 0.f;
    float4 accA, accB, xrvA, xrvB, resA, resB;
    uint2 xpkA[EB], xpkB[EB];
    float ceyA[EB], cezA[EB], cewA[EB], ceyB[EB], cezB[EB], cewB[EB];

    for (int dA = wave; dA < Nn; dA += 2 * nwaves) {
        int dB = dA + nwaves;
        LOAD_META(A, dA);
        LOAD_META(B, dB);
        ISSUE(A);
        ISSUE(B);
        while (i0A < endA || i0B < endB) {
            COMPUTE(A);
            ISSUE(A);
            COMPUTE(B);
            ISSUE(B);
        }
        EPILOGUE(A, dA);
        if (dB < Nn) EPILOGUE(B, dB);
    }
}

// ---------------------------------------------------------------- pooling
__global__ __launch_bounds__(256) void pool_kernel(const float* __restrict__ h,
                                                   const int* __restrict__ batch,
                                                   float* __restrict__ pooled,
                                                   int* __restrict__ cnt, int Nn) {
    int idx = blockIdx.x * 256 + threadIdx.x;
    int n = idx >> 6, c = idx & 63;
    if (n < Nn) {
        int g = batch[n];
        atomicAdd(&pooled[(size_t)g * 64 + c], h[(size_t)n * 64 + c]);
        if (c == 0) atomicAdd(&cnt[g], 1);
    }
}

// ---------------------------------------------------------------- MLP head
__global__ __launch_bounds__(64) void head_kernel(const float* __restrict__ pooled,
                                                  const int* __restrict__ cnt,
                                                  const float* __restrict__ Wo1,
                                                  const float* __restrict__ bo1,
                                                  const float* __restrict__ Wo2,
                                                  const float* __restrict__ bo2,
                                                  float* __restrict__ out, int Gg) {
    int g = blockIdx.x;
    int t = threadIdx.x;
    __shared__ float sp[64];
    float c = fmaxf((float)cnt[g], 1.f);
    sp[t] = pooled[(size_t)g * 64 + t] / c;
    __syncthreads();
    float hid = 0.f;
    if (t < 32) {
        hid = bo1[t];
        for (int k = 0; k < 64; k++) hid += sp[k] * Wo1[k * 32 + t];
        hid = hid > 0.f ? hid : expm1f(hid);
        hid *= Wo2[t];
    }
#pragma unroll
    for (int off = 32; off; off >>= 1) hid += __shfl_xor(hid, off);
    if (t == 0) out[g] = hid + bo2[0];
}

extern "C" void kernel_launch(void* const* d_in, const int* in_sizes, int n_in,
                              void* d_out, int out_size, void* d_ws, size_t ws_size,
                              hipStream_t stream) {
    const float* x   = (const float*)d_in[0];
    const int*   ei  = (const int*)d_in[1];
    const int*   bat = (const int*)d_in[2];
    const float* ea  = (const float*)d_in[3];
    const float* W0l = (const float*)d_in[4];
    const float* b0l = (const float*)d_in[5];
    const float* W0r = (const float*)d_in[6];
    const float* W0e = (const float*)d_in[7];
    const float* a0  = (const float*)d_in[8];
    const float* c0  = (const float*)d_in[9];
    const float* Wl  = (const float*)d_in[10];
    const float* bl  = (const float*)d_in[11];
    const float* Wr  = (const float*)d_in[12];
    const float* We  = (const float*)d_in[13];
    const float* a   = (const float*)d_in[14];
    const float* cb  = (const float*)d_in[15];
    const float* bng = (const float*)d_in[16];
    const float* bnb = (const float*)d_in[17];
    const float* bnm = (const float*)d_in[18];
    const float* bnv = (const float*)d_in[19];
    const float* Wo1 = (const float*)d_in[20];
    const float* bo1 = (const float*)d_in[21];
    const float* Wo2 = (const float*)d_in[22];
    const float* bo2 = (const float*)d_in[23];

    int Nn = in_sizes[2];
    int Ee = in_sizes[1] / 2;
    int Gg = out_size;
    const int* srcv = ei;
    const int* dstv = ei + Ee;

    char* w = (char*)d_ws;
    auto alloc = [&](size_t bytes) {
        char* p = w;
        w += (bytes + 255) & ~(size_t)255;
        return p;
    };
    __half* xlb    = (__half*)alloc((size_t)Nn * 256 * 2);
    float*  xrb    = (float*)alloc((size_t)Nn * 256 * 4);
    float*  hbuf   = (float*)alloc((size_t)Nn * 64 * 4);
    int*    deg    = (int*)alloc((size_t)Nn * 4);
    int*    rowptr = (int*)alloc((size_t)(Nn + 1) * 4);
    int*    cursor = (int*)alloc((size_t)Nn * 4);
    float4* csr4   = (float4*)alloc((size_t)Ee * 16);
    float*  pooled = (float*)alloc((size_t)Gg * 64 * 4);
    int*    cnt    = (int*)alloc((size_t)Gg * 4);
    int*    bsum   = (int*)alloc(256 * 4);
    float*  epi    = (float*)alloc(4 * 128 * 4);

    int nscan = (Nn + SCAN_ELEMS - 1) / SCAN_ELEMS;  // <=256 for Nn<=262144

    // CSR build + epilogue constants
    hipMemsetAsync(deg, 0, (size_t)Nn * 4, stream);
    count_kernel<<<(Ee + 255) / 256, 256, 0, stream>>>(dstv, deg, Ee);
    scan_phase1<<<nscan, 256, 0, stream>>>(deg, bsum, Nn);
    scan_phase2<<<1, 256, 0, stream>>>(bsum, nscan, rowptr, Nn);
    scan_phase3<<<nscan, 256, 0, stream>>>(deg, bsum, rowptr, cursor, Nn);
    scatter_kernel<<<(Ee + 255) / 256, 256, 0, stream>>>(srcv, dstv, ea, cursor, csr4, Ee);
    bnprep_kernel<<<1, 256, 0, stream>>>(c0, cb, bng, bnb, bnm, bnv, epi);

    int gatg = 2048;  // persistent: 2048 blocks x 4 waves = 8192 waves

    // layer 0 (K=9)
    gemm2_kernel<<<(Nn + GROWS - 1) / GROWS, 256, 0, stream>>>(x, 9, W0l, b0l, W0r, xlb, xrb, Nn);
    gat_kernel<<<gatg, 256, 0, stream>>>(xlb, xrb, W0e, a0, epi,
                                         rowptr, csr4, hbuf, nullptr, Nn);
    // 3 residual layers (K=64)
    for (int i = 0; i < 3; i++) {
        gemm2_kernel<<<(Nn + GROWS - 1) / GROWS, 256, 0, stream>>>(
            hbuf, 64, Wl + (size_t)i * 64 * 256, bl + (size_t)i * 256,
            Wr + (size_t)i * 64 * 256, xlb, xrb, Nn);
        gat_kernel<<<gatg, 256, 0, stream>>>(
            xlb, xrb, We + (size_t)i * 768, a + (size_t)i * 256, epi + (size_t)(i + 1) * 128,
            rowptr, csr4, hbuf, hbuf, Nn);
    }

    // global mean pool + head
    hipMemsetAsync(pooled, 0, (size_t)Gg * 64 * 4, stream);
    hipMemsetAsync(cnt, 0, (size_t)Gg * 4, stream);
    pool_kernel<<<((size_t)Nn * 64 + 255) / 256, 256, 0, stream>>>(hbuf, bat, pooled, cnt, Nn);
    head_kernel<<<Gg, 64, 0, stream>>>(pooled, cnt, Wo1, bo1, Wo2, bo2, (float*)d_out, Gg);
}

// Round 8
// 689.065 us; speedup vs baseline: 1.2452x; 1.2452x over previous
//
#include <hip/hip_runtime.h>
#include <hip/hip_fp16.h>
#include <math.h>

// ---------------------------------------------------------------- CSR build
__global__ __launch_bounds__(256) void count_kernel(const int* __restrict__ dst,
                                                    int* __restrict__ deg, int E) {
    int e = blockIdx.x * 256 + threadIdx.x;
    if (e < E) atomicAdd(&deg[dst[e]], 1);
}

#define SCAN_TPB 256
#define SCAN_VPT 4
#define SCAN_ELEMS (SCAN_TPB * SCAN_VPT)  // 1024

__global__ __launch_bounds__(256) void scan_phase1(const int* __restrict__ deg,
                                                   int* __restrict__ bsum, int n) {
    __shared__ int sh[SCAN_TPB];
    int base = blockIdx.x * SCAN_ELEMS + threadIdx.x * SCAN_VPT;
    int s = 0;
#pragma unroll
    for (int j = 0; j < SCAN_VPT; j++) { int i = base + j; if (i < n) s += deg[i]; }
    sh[threadIdx.x] = s;
    __syncthreads();
    for (int off = 128; off; off >>= 1) {
        if (threadIdx.x < (unsigned)off) sh[threadIdx.x] += sh[threadIdx.x + off];
        __syncthreads();
    }
    if (threadIdx.x == 0) bsum[blockIdx.x] = sh[0];
}

__global__ __launch_bounds__(256) void scan_phase2(int* __restrict__ bsum, int nb,
                                                   int* __restrict__ rowptr, int n) {
    __shared__ int sh[256];
    int v = (threadIdx.x < (unsigned)nb) ? bsum[threadIdx.x] : 0;
    sh[threadIdx.x] = v;
    __syncthreads();
    for (int off = 1; off < 256; off <<= 1) {
        int t = (threadIdx.x >= (unsigned)off) ? sh[threadIdx.x - off] : 0;
        __syncthreads();
        sh[threadIdx.x] += t;
        __syncthreads();
    }
    if (threadIdx.x < (unsigned)nb) bsum[threadIdx.x] = sh[threadIdx.x] - v;  // exclusive
    if (threadIdx.x == 0) rowptr[n] = sh[255];                                // total
}

__global__ __launch_bounds__(256) void scan_phase3(const int* __restrict__ deg,
                                                   const int* __restrict__ bsum,
                                                   int* __restrict__ rowptr,
                                                   int* __restrict__ cursor, int n) {
    __shared__ int sh[SCAN_TPB];
    int tid = threadIdx.x;
    int base = blockIdx.x * SCAN_ELEMS + tid * SCAN_VPT;
    int v[SCAN_VPT];
    int s = 0;
#pragma unroll
    for (int j = 0; j < SCAN_VPT; j++) { int i = base + j; v[j] = (i < n) ? deg[i] : 0; s += v[j]; }
    sh[tid] = s;
    __syncthreads();
    for (int off = 1; off < SCAN_TPB; off <<= 1) {
        int t = (tid >= off) ? sh[tid - off] : 0;
        __syncthreads();
        sh[tid] += t;
        __syncthreads();
    }
    int ex = sh[tid] - s + bsum[blockIdx.x];
#pragma unroll
    for (int j = 0; j < SCAN_VPT; j++) {
        int i = base + j;
        if (i < n) { rowptr[i] = ex; cursor[i] = ex; ex += v[j]; }
    }
}

// CSR record: {src_as_float_bits, ea0, ea1, ea2} — one s_load_dwordx4 per edge
__global__ __launch_bounds__(256) void scatter_kernel(const int* __restrict__ src,
                                                      const int* __restrict__ dst,
                                                      const float* __restrict__ ea,
                                                      int* __restrict__ cursor,
                                                      float4* __restrict__ csr4, int E) {
    int e = blockIdx.x * 256 + threadIdx.x;
    if (e < E) {
        int d = dst[e];
        int pos = atomicAdd(&cursor[d], 1);
        size_t eb3 = (size_t)e * 3;
        csr4[pos] = make_float4(__int_as_float(src[e]), ea[eb3], ea[eb3 + 1], ea[eb3 + 2]);
    }
}

// ------------- epilogue constants: A = 0.25*g*rsqrt(v+eps); B = (bias-m)*s+b
__global__ __launch_bounds__(256) void bnprep_kernel(const float* __restrict__ c0,
                                                     const float* __restrict__ cb,   // [3][64]
                                                     const float* __restrict__ bng,
                                                     const float* __restrict__ bnb,
                                                     const float* __restrict__ bnm,
                                                     const float* __restrict__ bnv,
                                                     float* __restrict__ epi) {      // [4][2][64]
    int t = threadIdx.x;           // exactly 256 = 4 layers x 64 channels
    int l = t >> 6, c = t & 63;
    float s = bng[l * 64 + c] * rsqrtf(bnv[l * 64 + c] + 1e-5f);
    float bias = (l == 0) ? c0[c] : cb[(l - 1) * 64 + c];
    epi[l * 128 + c] = 0.25f * s;
    epi[l * 128 + 64 + c] = (bias - bnm[l * 64 + c]) * s + bnb[l * 64 + c];
}

// ----------------- xl = fp16(x@Wl+bl), xr = fp16(x@Wr) [both gather payloads]
#define GROWS 32
__global__ __launch_bounds__(256) void gemm2_kernel(const float* __restrict__ xin, int K,
                                                    const float* __restrict__ Wl,
                                                    const float* __restrict__ bl,
                                                    const float* __restrict__ Wr,
                                                    __half* __restrict__ xl,
                                                    __half* __restrict__ xr, int Nn) {
    __shared__ __align__(16) float sh[GROWS][64];
    int j = threadIdx.x;  // output column 0..255
    int n0 = blockIdx.x * GROWS;
    for (int t = threadIdx.x; t < GROWS * K; t += 256) {
        int r = t / K, k = t - r * K;
        int n = n0 + r;
        sh[r][k] = (n < Nn) ? xin[(size_t)n * K + k] : 0.f;
    }
    __syncthreads();
    float accl[GROWS], accr[GROWS];
    float b = bl[j];
#pragma unroll
    for (int r = 0; r < GROWS; r++) { accl[r] = b; accr[r] = 0.f; }
    if (K == 64) {
        for (int k4 = 0; k4 < 16; k4++) {
            int k = k4 * 4;
            float wl0 = Wl[(k + 0) * 256 + j], wl1 = Wl[(k + 1) * 256 + j];
            float wl2 = Wl[(k + 2) * 256 + j], wl3 = Wl[(k + 3) * 256 + j];
            float wr0 = Wr[(k + 0) * 256 + j], wr1 = Wr[(k + 1) * 256 + j];
            float wr2 = Wr[(k + 2) * 256 + j], wr3 = Wr[(k + 3) * 256 + j];
#pragma unroll
            for (int r = 0; r < GROWS; r++) {
                float4 h4 = *(const float4*)&sh[r][k];
                accl[r] += h4.x * wl0 + h4.y * wl1 + h4.z * wl2 + h4.w * wl3;
                accr[r] += h4.x * wr0 + h4.y * wr1 + h4.z * wr2 + h4.w * wr3;
            }
        }
    } else {
        for (int k = 0; k < K; k++) {
            float wl = Wl[k * 256 + j], wr = Wr[k * 256 + j];
#pragma unroll
            for (int r = 0; r < GROWS; r++) { accl[r] += sh[r][k] * wl; accr[r] += sh[r][k] * wr; }
        }
    }
    for (int r = 0; r < GROWS; r++) {
        int n = n0 + r;
        if (n < Nn) {
            xl[(size_t)n * 256 + j] = __float2half_rn(accl[r]);
            xr[(size_t)n * 256 + j] = __float2half_rn(accr[r]);
        }
    }
}

// --------------------------- fused GATv2: persistent wave-per-node (R6 base)
// lane = h*16 + cg holds channels cg*4..cg*4+3 of head h.
// Wave index scalarized once -> d, rowptr[d], csr4[idx] all provably uniform
// (s_load path, no per-edge readfirstlane). Next node's rowptr (SGPR) and xr
// row (2 VGPR) prefetched at top of node body, consumed at the roll.
// Softmax with implicit C=0 (exact for this model's O(0.3) scores).
#define EB 8
__global__ __launch_bounds__(256) void gat_kernel(const __half* __restrict__ xl,
                                                  const __half* __restrict__ xr,
                                                  const float* __restrict__ We,   // [3,256]
                                                  const float* __restrict__ att,  // [256]
                                                  const float* __restrict__ epi,  // [2][64]
                                                  const int* __restrict__ rowptr,
                                                  const float4* __restrict__ csr4,
                                                  float* __restrict__ hout,       // [N,64]
                                                  const float* __restrict__ hres, // [N,64] or null
                                                  int Nn) {
    int tid = threadIdx.x;
    int lane = tid & 63;
    int w = __builtin_amdgcn_readfirstlane(tid >> 6);   // scalar wave-in-block
    int wave = blockIdx.x * 4 + w;                      // scalar
    int nwaves = gridDim.x * 4;

    float4 we0 = *(const float4*)&We[lane * 4];
    float4 we1 = *(const float4*)&We[256 + lane * 4];
    float4 we2 = *(const float4*)&We[512 + lane * 4];
    float4 attv = *(const float4*)&att[lane * 4];
    float4 att02 = make_float4(0.2f * attv.x, 0.2f * attv.y, 0.2f * attv.z, 0.2f * attv.w);
    float4 eA = *(const float4*)&epi[(lane & 15) * 4];
    float4 eB4 = *(const float4*)&epi[64 + (lane & 15) * 4];

    int d = wave;
    if (d >= Nn) return;
    int beg = rowptr[d];            // scalar loads
    int end = rowptr[d + 1];
    uint2 xrp = *(const uint2*)(xr + ((size_t)d << 8) + (lane << 2));

    while (d < Nn) {
        // ---- prefetch next node's meta (SGPR + 2 VGPR), consumed at roll
        int dn = d + nwaves;
        int begn = 0, endn = 0;
        uint2 xrpn = make_uint2(0u, 0u);
        if (dn < Nn) {
            begn = rowptr[dn];
            endn = rowptr[dn + 1];
            xrpn = *(const uint2*)(xr + ((size_t)dn << 8) + (lane << 2));
        }
        // ---- current node
        float2 xr0 = __half22float2(*(const __half2*)&xrp.x);
        float2 xr1 = __half22float2(*(const __half2*)&xrp.y);

        float l_run = 0.f;
        float4 acc = make_float4(0.f, 0.f, 0.f, 0.f);

        for (int i0 = beg; i0 < end; i0 += EB) {
            uint2 xpk[EB];
            float p[EB];
#pragma unroll
            for (int j = 0; j < EB; j++) {
                int idx = i0 + j;
                if (idx < end) {
                    float4 ce = csr4[idx];            // uniform -> s_load_dwordx4
                    int sn = __float_as_int(ce.x);    // already SGPR
                    uint2 v = *(const uint2*)(xl + ((size_t)sn << 8) + (lane << 2));
                    xpk[j] = v;
                    float2 f0 = __half22float2(*(const __half2*)&v.x);
                    float2 f1 = __half22float2(*(const __half2*)&v.y);
                    float tx = fmaf(ce.y, we0.x, fmaf(ce.z, we1.x, fmaf(ce.w, we2.x, xr0.x))) + f0.x;
                    float ty = fmaf(ce.y, we0.y, fmaf(ce.z, we1.y, fmaf(ce.w, we2.y, xr0.y))) + f0.y;
                    float tz = fmaf(ce.y, we0.z, fmaf(ce.z, we1.z, fmaf(ce.w, we2.z, xr1.x))) + f1.x;
                    float tw = fmaf(ce.y, we0.w, fmaf(ce.z, we1.w, fmaf(ce.w, we2.w, xr1.y))) + f1.y;
                    float pp = tx * (tx > 0.f ? attv.x : att02.x);
                    pp = fmaf(ty, (ty > 0.f ? attv.y : att02.y), pp);
                    pp = fmaf(tz, (tz > 0.f ? attv.z : att02.z), pp);
                    pp = fmaf(tw, (tw > 0.f ? attv.w : att02.w), pp);
                    p[j] = pp;
                } else {
                    p[j] = -INFINITY;   // exp(-inf)=0 -> padding contributes nothing
                    xpk[j] = make_uint2(0u, 0u);
                }
            }
            // 16-lane reduce within each head group
#pragma unroll
            for (int off = 1; off < 16; off <<= 1) {
#pragma unroll
                for (int j = 0; j < EB; j++) p[j] += __shfl_xor(p[j], off);
            }
            // fixed-shift softmax accumulate (no max tracking)
#pragma unroll
            for (int j = 0; j < EB; j++) {
                float wv = __expf(p[j]);
                float2 f0 = __half22float2(*(const __half2*)&xpk[j].x);
                float2 f1 = __half22float2(*(const __half2*)&xpk[j].y);
                acc.x = fmaf(wv, f0.x, acc.x);
                acc.y = fmaf(wv, f0.y, acc.y);
                acc.z = fmaf(wv, f1.x, acc.z);
                acc.w = fmaf(wv, f1.y, acc.w);
                l_run += wv;
            }
        }
        // ---- epilogue: head-mean + BN/bias (precomputed) + ELU + residual
        float inv = (end > beg) ? 1.f / l_run : 0.f;
        float4 o = make_float4(acc.x * inv, acc.y * inv, acc.z * inv, acc.w * inv);
#pragma unroll
        for (int off = 16; off < 64; off <<= 1) {
            o.x += __shfl_xor(o.x, off);
            o.y += __shfl_xor(o.y, off);
            o.z += __shfl_xor(o.z, off);
            o.w += __shfl_xor(o.w, off);
        }
        if (lane < 16) {
            float vx = fmaf(o.x, eA.x, eB4.x);
            float vy = fmaf(o.y, eA.y, eB4.y);
            float vz = fmaf(o.z, eA.z, eB4.z);
            float vw = fmaf(o.w, eA.w, eB4.w);
            vx = vx > 0.f ? vx : expm1f(vx);
            vy = vy > 0.f ? vy : expm1f(vy);
            vz = vz > 0.f ? vz : expm1f(vz);
            vw = vw > 0.f ? vw : expm1f(vw);
            if (hres) {
                float4 r4 = *(const float4*)&hres[((size_t)d << 6) + (lane << 2)];
                vx += r4.x; vy += r4.y; vz += r4.z; vw += r4.w;
            }
            *(float4*)&hout[((size_t)d << 6) + (lane << 2)] = make_float4(vx, vy, vz, vw);
        }
        // ---- roll to prefetched node
        d = dn; beg = begn; end = endn; xrp = xrpn;
    }
}

// ---------------------------------------------------------------- pooling
__global__ __launch_bounds__(256) void pool_kernel(const float* __restrict__ h,
                                                   const int* __restrict__ batch,
                                                   float* __restrict__ pooled,
                                                   int* __restrict__ cnt, int Nn) {
    int idx = blockIdx.x * 256 + threadIdx.x;
    int n = idx >> 6, c = idx & 63;
    if (n < Nn) {
        int g = batch[n];
        atomicAdd(&pooled[(size_t)g * 64 + c], h[(size_t)n * 64 + c]);
        if (c == 0) atomicAdd(&cnt[g], 1);
    }
}

// ---------------------------------------------------------------- MLP head
__global__ __launch_bounds__(64) void head_kernel(const float* __restrict__ pooled,
                                                  const int* __restrict__ cnt,
                                                  const float* __restrict__ Wo1,
                                                  const float* __restrict__ bo1,
                                                  const float* __restrict__ Wo2,
                                                  const float* __restrict__ bo2,
                                                  float* __restrict__ out, int Gg) {
    int g = blockIdx.x;
    int t = threadIdx.x;
    __shared__ float sp[64];
    float c = fmaxf((float)cnt[g], 1.f);
    sp[t] = pooled[(size_t)g * 64 + t] / c;
    __syncthreads();
    float hid = 0.f;
    if (t < 32) {
        hid = bo1[t];
        for (int k = 0; k < 64; k++) hid += sp[k] * Wo1[k * 32 + t];
        hid = hid > 0.f ? hid : expm1f(hid);
        hid *= Wo2[t];
    }
#pragma unroll
    for (int off = 32; off; off >>= 1) hid += __shfl_xor(hid, off);
    if (t == 0) out[g] = hid + bo2[0];
}

extern "C" void kernel_launch(void* const* d_in, const int* in_sizes, int n_in,
                              void* d_out, int out_size, void* d_ws, size_t ws_size,
                              hipStream_t stream) {
    const float* x   = (const float*)d_in[0];
    const int*   ei  = (const int*)d_in[1];
    const int*   bat = (const int*)d_in[2];
    const float* ea  = (const float*)d_in[3];
    const float* W0l = (const float*)d_in[4];
    const float* b0l = (const float*)d_in[5];
    const float* W0r = (const float*)d_in[6];
    const float* W0e = (const float*)d_in[7];
    const float* a0  = (const float*)d_in[8];
    const float* c0  = (const float*)d_in[9];
    const float* Wl  = (const float*)d_in[10];
    const float* bl  = (const float*)d_in[11];
    const float* Wr  = (const float*)d_in[12];
    const float* We  = (const float*)d_in[13];
    const float* a   = (const float*)d_in[14];
    const float* cb  = (const float*)d_in[15];
    const float* bng = (const float*)d_in[16];
    const float* bnb = (const float*)d_in[17];
    const float* bnm = (const float*)d_in[18];
    const float* bnv = (const float*)d_in[19];
    const float* Wo1 = (const float*)d_in[20];
    const float* bo1 = (const float*)d_in[21];
    const float* Wo2 = (const float*)d_in[22];
    const float* bo2 = (const float*)d_in[23];

    int Nn = in_sizes[2];
    int Ee = in_sizes[1] / 2;
    int Gg = out_size;
    const int* srcv = ei;
    const int* dstv = ei + Ee;

    char* w = (char*)d_ws;
    auto alloc = [&](size_t bytes) {
        char* p = w;
        w += (bytes + 255) & ~(size_t)255;
        return p;
    };
    __half* xlb    = (__half*)alloc((size_t)Nn * 256 * 2);
    __half* xrb    = (__half*)alloc((size_t)Nn * 256 * 2);
    float*  hbuf   = (float*)alloc((size_t)Nn * 64 * 4);
    int*    deg    = (int*)alloc((size_t)Nn * 4);
    int*    rowptr = (int*)alloc((size_t)(Nn + 1) * 4);
    int*    cursor = (int*)alloc((size_t)Nn * 4);
    float4* csr4   = (float4*)alloc((size_t)Ee * 16);
    float*  pooled = (float*)alloc((size_t)Gg * 64 * 4);
    int*    cnt    = (int*)alloc((size_t)Gg * 4);
    int*    bsum   = (int*)alloc(256 * 4);
    float*  epi    = (float*)alloc(4 * 128 * 4);

    int nscan = (Nn + SCAN_ELEMS - 1) / SCAN_ELEMS;  // <=256 for Nn<=262144

    // CSR build + epilogue constants
    hipMemsetAsync(deg, 0, (size_t)Nn * 4, stream);
    count_kernel<<<(Ee + 255) / 256, 256, 0, stream>>>(dstv, deg, Ee);
    scan_phase1<<<nscan, 256, 0, stream>>>(deg, bsum, Nn);
    scan_phase2<<<1, 256, 0, stream>>>(bsum, nscan, rowptr, Nn);
    scan_phase3<<<nscan, 256, 0, stream>>>(deg, bsum, rowptr, cursor, Nn);
    scatter_kernel<<<(Ee + 255) / 256, 256, 0, stream>>>(srcv, dstv, ea, cursor, csr4, Ee);
    bnprep_kernel<<<1, 256, 0, stream>>>(c0, cb, bng, bnb, bnm, bnv, epi);

    int gatg = 2048;  // persistent: 2048 blocks x 4 waves = 8192 waves

    // layer 0 (K=9)
    gemm2_kernel<<<(Nn + GROWS - 1) / GROWS, 256, 0, stream>>>(x, 9, W0l, b0l, W0r, xlb, xrb, Nn);
    gat_kernel<<<gatg, 256, 0, stream>>>(xlb, xrb, W0e, a0, epi,
                                         rowptr, csr4, hbuf, nullptr, Nn);
    // 3 residual layers (K=64)
    for (int i = 0; i < 3; i++) {
        gemm2_kernel<<<(Nn + GROWS - 1) / GROWS, 256, 0, stream>>>(
            hbuf, 64, Wl + (size_t)i * 64 * 256, bl + (size_t)i * 256,
            Wr + (size_t)i * 64 * 256, xlb, xrb, Nn);
        gat_kernel<<<gatg, 256, 0, stream>>>(
            xlb, xrb, We + (size_t)i * 768, a + (size_t)i * 256, epi + (size_t)(i + 1) * 128,
            rowptr, csr4, hbuf, hbuf, Nn);
    }

    // global mean pool + head
    hipMemsetAsync(pooled, 0, (size_t)Gg * 64 * 4, stream);
    hipMemsetAsync(cnt, 0, (size_t)Gg * 4, stream);
    pool_kernel<<<((size_t)Nn * 64 + 255) / 256, 256, 0, stream>>>(hbuf, bat, pooled, cnt, Nn);
    head_kernel<<<Gg, 64, 0, stream>>>(pooled, cnt, Wo1, bo1, Wo2, bo2, (float*)d_out, Gg);
}

// Round 9
// 551.688 us; speedup vs baseline: 1.5553x; 1.2490x over previous
//
#include <hip/hip_runtime.h>
#include <hip/hip_fp16.h>
#include <math.h>

typedef _Float16 h8 __attribute__((ext_vector_type(8)));
typedef float f4 __attribute__((ext_vector_type(4)));

// ---------------------------------------------------------------- CSR build
__global__ __launch_bounds__(256) void count_kernel(const int* __restrict__ dst,
                                                    int* __restrict__ deg, int E) {
    int e = blockIdx.x * 256 + threadIdx.x;
    if (e < E) atomicAdd(&deg[dst[e]], 1);
}

#define SCAN_TPB 256
#define SCAN_VPT 4
#define SCAN_ELEMS (SCAN_TPB * SCAN_VPT)  // 1024

__global__ __launch_bounds__(256) void scan_phase1(const int* __restrict__ deg,
                                                   int* __restrict__ bsum, int n) {
    __shared__ int sh[SCAN_TPB];
    int base = blockIdx.x * SCAN_ELEMS + threadIdx.x * SCAN_VPT;
    int s = 0;
#pragma unroll
    for (int j = 0; j < SCAN_VPT; j++) { int i = base + j; if (i < n) s += deg[i]; }
    sh[threadIdx.x] = s;
    __syncthreads();
    for (int off = 128; off; off >>= 1) {
        if (threadIdx.x < (unsigned)off) sh[threadIdx.x] += sh[threadIdx.x + off];
        __syncthreads();
    }
    if (threadIdx.x == 0) bsum[blockIdx.x] = sh[0];
}

__global__ __launch_bounds__(256) void scan_phase2(int* __restrict__ bsum, int nb,
                                                   int* __restrict__ rowptr, int n) {
    __shared__ int sh[256];
    int v = (threadIdx.x < (unsigned)nb) ? bsum[threadIdx.x] : 0;
    sh[threadIdx.x] = v;
    __syncthreads();
    for (int off = 1; off < 256; off <<= 1) {
        int t = (threadIdx.x >= (unsigned)off) ? sh[threadIdx.x - off] : 0;
        __syncthreads();
        sh[threadIdx.x] += t;
        __syncthreads();
    }
    if (threadIdx.x < (unsigned)nb) bsum[threadIdx.x] = sh[threadIdx.x] - v;  // exclusive
    if (threadIdx.x == 0) rowptr[n] = sh[255];                                // total
}

__global__ __launch_bounds__(256) void scan_phase3(const int* __restrict__ deg,
                                                   const int* __restrict__ bsum,
                                                   int* __restrict__ rowptr,
                                                   int* __restrict__ cursor, int n) {
    __shared__ int sh[SCAN_TPB];
    int tid = threadIdx.x;
    int base = blockIdx.x * SCAN_ELEMS + tid * SCAN_VPT;
    int v[SCAN_VPT];
    int s = 0;
#pragma unroll
    for (int j = 0; j < SCAN_VPT; j++) { int i = base + j; v[j] = (i < n) ? deg[i] : 0; s += v[j]; }
    sh[tid] = s;
    __syncthreads();
    for (int off = 1; off < SCAN_TPB; off <<= 1) {
        int t = (tid >= off) ? sh[tid - off] : 0;
        __syncthreads();
        sh[tid] += t;
        __syncthreads();
    }
    int ex = sh[tid] - s + bsum[blockIdx.x];
#pragma unroll
    for (int j = 0; j < SCAN_VPT; j++) {
        int i = base + j;
        if (i < n) { rowptr[i] = ex; cursor[i] = ex; ex += v[j]; }
    }
}

// CSR record: {src_as_float_bits, ea0, ea1, ea2} — one s_load_dwordx4 per edge
__global__ __launch_bounds__(256) void scatter_kernel(const int* __restrict__ src,
                                                      const int* __restrict__ dst,
                                                      const float* __restrict__ ea,
                                                      int* __restrict__ cursor,
                                                      float4* __restrict__ csr4, int E) {
    int e = blockIdx.x * 256 + threadIdx.x;
    if (e < E) {
        int d = dst[e];
        int pos = atomicAdd(&cursor[d], 1);
        size_t eb3 = (size_t)e * 3;
        csr4[pos] = make_float4(__int_as_float(src[e]), ea[eb3], ea[eb3 + 1], ea[eb3 + 2]);
    }
}

// ------------- epilogue constants: A = 0.25*g*rsqrt(v+eps); B = (bias-m)*s+b
__global__ __launch_bounds__(256) void bnprep_kernel(const float* __restrict__ c0,
                                                     const float* __restrict__ cb,   // [3][64]
                                                     const float* __restrict__ bng,
                                                     const float* __restrict__ bnb,
                                                     const float* __restrict__ bnm,
                                                     const float* __restrict__ bnv,
                                                     float* __restrict__ epi) {      // [4][2][64]
    int t = threadIdx.x;           // exactly 256 = 4 layers x 64 channels
    int l = t >> 6, c = t & 63;
    float s = bng[l * 64 + c] * rsqrtf(bnv[l * 64 + c] + 1e-5f);
    float bias = (l == 0) ? c0[c] : cb[(l - 1) * 64 + c];
    epi[l * 128 + c] = 0.25f * s;
    epi[l * 128 + 64 + c] = (bias - bnm[l * 64 + c]) * s + bnb[l * 64 + c];
}

// ------------- weight prep: pack Wl|Wr (fp16, zero-padded) into MFMA A-frag
// order. Wp[layer][((gct*2 + ks)*64 + lane)*8 + j] = W_side[k][c], where
// side = (gct<16 ? Wl : Wr), c = (gct&15)*16 + (lane&15),
// k = ks*32 + (lane>>4)*8 + j (0 if k >= K). Layer stride 32768 halfs.
__global__ __launch_bounds__(256) void wprep_kernel(const float* __restrict__ W0l,
                                                    const float* __restrict__ W0r,
                                                    const float* __restrict__ Wl,
                                                    const float* __restrict__ Wr,
                                                    __half* __restrict__ Wp) {
    int t = blockIdx.x * 256 + threadIdx.x;   // 4 layers * 4096
    int layer = t >> 12;
    int r = t & 4095;
    int lane = r & 63;
    int ks = (r >> 6) & 1;
    int gct = r >> 7;                          // 0..31
    int K = (layer == 0) ? 9 : 64;
    const float* Wsrc;
    if (layer == 0) Wsrc = (gct < 16) ? W0l : W0r;
    else            Wsrc = ((gct < 16) ? Wl : Wr) + (size_t)(layer - 1) * 64 * 256;
    int cl = ((gct & 15) << 4) + (lane & 15);
    int k0 = (ks << 5) + ((lane >> 4) << 3);
    __half vals[8] __attribute__((aligned(16)));
#pragma unroll
    for (int j = 0; j < 8; j++) {
        int k = k0 + j;
        vals[j] = __float2half_rn((k < K) ? Wsrc[(size_t)k * 256 + cl] : 0.f);
    }
    *(uint4*)(Wp + (size_t)t * 8) = *(const uint4*)vals;
}

// ----------------- MFMA gemm2: xl = fp16(x@Wl+bl), xr = fp16(x@Wr).
// Transposed mapping: D-tile = Wt[16 cols] x Xt[16 nodes]; A = W^T frags
// (from packed Wp, one uint4 load each), B = x^T frags (8 contiguous fp32
// per lane -> cvt). D frag: node = lane&15, col = (lane>>4)*4 + reg ->
// 4 consecutive output cols per lane -> single 8B store per tile.
// Block = 4 waves x (8 col-tiles each) over 32 nodes; no LDS, no syncs.
template <int K>
__global__ __launch_bounds__(256) void gemm2_mfma_kernel(const float* __restrict__ xin,
                                                         const __half* __restrict__ Wp,
                                                         const float* __restrict__ bl,
                                                         __half* __restrict__ xl,
                                                         __half* __restrict__ xr, int Nn) {
    constexpr int NKS = (K > 32) ? 2 : 1;
    int tid = threadIdx.x;
    int lane = tid & 63;
    int wv = tid >> 6;           // 0..3
    int nb = blockIdx.x * 32;
    int l15 = lane & 15;
    int lg = lane >> 4;          // 0..3

    // A fragments (weights), resident: 8 col-tiles x NKS
    h8 afr[8][NKS];
#pragma unroll
    for (int i = 0; i < 8; i++) {
        int gct = wv * 8 + i;
#pragma unroll
        for (int ks = 0; ks < NKS; ks++)
            afr[i][ks] = *(const h8*)(Wp + (((size_t)(gct * 2 + ks)) * 64 + lane) * 8);
    }
    // B fragments (x rows -> fp16)
    h8 bfr[2][NKS];
#pragma unroll
    for (int nt = 0; nt < 2; nt++) {
        int node = nb + nt * 16 + l15;
        int nc = node < Nn ? node : Nn - 1;
#pragma unroll
        for (int ks = 0; ks < NKS; ks++) {
            int k0 = ks * 32 + lg * 8;
            h8 b;
            if (K == 64) {
                float4 f0 = *(const float4*)(xin + (size_t)nc * 64 + k0);
                float4 f1 = *(const float4*)(xin + (size_t)nc * 64 + k0 + 4);
                b[0] = (_Float16)f0.x; b[1] = (_Float16)f0.y;
                b[2] = (_Float16)f0.z; b[3] = (_Float16)f0.w;
                b[4] = (_Float16)f1.x; b[5] = (_Float16)f1.y;
                b[6] = (_Float16)f1.z; b[7] = (_Float16)f1.w;
            } else {
#pragma unroll
                for (int j = 0; j < 8; j++) {
                    int k = k0 + j;
                    b[j] = (_Float16)((k < K) ? xin[(size_t)nc * K + k] : 0.f);
                }
            }
            bfr[nt][ks] = b;
        }
    }
    // accumulators, init with bias on the xl side
    f4 acc[8][2];
#pragma unroll
    for (int i = 0; i < 8; i++) {
        int gct = wv * 8 + i;
        f4 ini;
        if (gct < 16) {
            float4 b4 = *(const float4*)(bl + (gct << 4) + (lg << 2));
            ini[0] = b4.x; ini[1] = b4.y; ini[2] = b4.z; ini[3] = b4.w;
        } else {
            ini[0] = 0.f; ini[1] = 0.f; ini[2] = 0.f; ini[3] = 0.f;
        }
        acc[i][0] = ini;
        acc[i][1] = ini;
    }
    // matrix core
#pragma unroll
    for (int i = 0; i < 8; i++)
#pragma unroll
        for (int nt = 0; nt < 2; nt++)
#pragma unroll
            for (int ks = 0; ks < NKS; ks++)
                acc[i][nt] = __builtin_amdgcn_mfma_f32_16x16x32_f16(
                    afr[i][ks], bfr[nt][ks], acc[i][nt], 0, 0, 0);
    // store: 4 consecutive cols per lane -> uint2
#pragma unroll
    for (int i = 0; i < 8; i++) {
        int gct = wv * 8 + i;
        __half* outp = (gct < 16) ? xl : xr;
        int cl = ((gct & 15) << 4) + (lg << 2);
#pragma unroll
        for (int nt = 0; nt < 2; nt++) {
            int node = nb + nt * 16 + l15;
            if (node < Nn) {
                __half h4[4] __attribute__((aligned(8)));
                h4[0] = __float2half_rn(acc[i][nt][0]);
                h4[1] = __float2half_rn(acc[i][nt][1]);
                h4[2] = __float2half_rn(acc[i][nt][2]);
                h4[3] = __float2half_rn(acc[i][nt][3]);
                *(uint2*)(outp + (size_t)node * 256 + cl) = *(const uint2*)h4;
            }
        }
    }
}

// --------------------------- fused GATv2: persistent wave-per-node (R8)
#define EB 8
__global__ __launch_bounds__(256) void gat_kernel(const __half* __restrict__ xl,
                                                  const __half* __restrict__ xr,
                                                  const float* __restrict__ We,   // [3,256]
                                                  const float* __restrict__ att,  // [256]
                                                  const float* __restrict__ epi,  // [2][64]
                                                  const int* __restrict__ rowptr,
                                                  const float4* __restrict__ csr4,
                                                  float* __restrict__ hout,       // [N,64]
                                                  const float* __restrict__ hres, // [N,64] or null
                                                  int Nn) {
    int tid = threadIdx.x;
    int lane = tid & 63;
    int w = __builtin_amdgcn_readfirstlane(tid >> 6);   // scalar wave-in-block
    int wave = blockIdx.x * 4 + w;                      // scalar
    int nwaves = gridDim.x * 4;

    float4 we0 = *(const float4*)&We[lane * 4];
    float4 we1 = *(const float4*)&We[256 + lane * 4];
    float4 we2 = *(const float4*)&We[512 + lane * 4];
    float4 attv = *(const float4*)&att[lane * 4];
    float4 att02 = make_float4(0.2f * attv.x, 0.2f * attv.y, 0.2f * attv.z, 0.2f * attv.w);
    float4 eA = *(const float4*)&epi[(lane & 15) * 4];
    float4 eB4 = *(const float4*)&epi[64 + (lane & 15) * 4];

    int d = wave;
    if (d >= Nn) return;
    int beg = rowptr[d];            // scalar loads
    int end = rowptr[d + 1];
    uint2 xrp = *(const uint2*)(xr + ((size_t)d << 8) + (lane << 2));

    while (d < Nn) {
        // ---- prefetch next node's meta (SGPR + 2 VGPR), consumed at roll
        int dn = d + nwaves;
        int begn = 0, endn = 0;
        uint2 xrpn = make_uint2(0u, 0u);
        if (dn < Nn) {
            begn = rowptr[dn];
            endn = rowptr[dn + 1];
            xrpn = *(const uint2*)(xr + ((size_t)dn << 8) + (lane << 2));
        }
        // ---- current node
        float2 xr0 = __half22float2(*(const __half2*)&xrp.x);
        float2 xr1 = __half22float2(*(const __half2*)&xrp.y);

        float l_run = 0.f;
        float4 acc = make_float4(0.f, 0.f, 0.f, 0.f);

        for (int i0 = beg; i0 < end; i0 += EB) {
            uint2 xpk[EB];
            float p[EB];
#pragma unroll
            for (int j = 0; j < EB; j++) {
                int idx = i0 + j;
                if (idx < end) {
                    float4 ce = csr4[idx];            // uniform -> s_load_dwordx4
                    int sn = __float_as_int(ce.x);    // already SGPR
                    uint2 v = *(const uint2*)(xl + ((size_t)sn << 8) + (lane << 2));
                    xpk[j] = v;
                    float2 f0 = __half22float2(*(const __half2*)&v.x);
                    float2 f1 = __half22float2(*(const __half2*)&v.y);
                    float tx = fmaf(ce.y, we0.x, fmaf(ce.z, we1.x, fmaf(ce.w, we2.x, xr0.x))) + f0.x;
                    float ty = fmaf(ce.y, we0.y, fmaf(ce.z, we1.y, fmaf(ce.w, we2.y, xr0.y))) + f0.y;
                    float tz = fmaf(ce.y, we0.z, fmaf(ce.z, we1.z, fmaf(ce.w, we2.z, xr1.x))) + f1.x;
                    float tw = fmaf(ce.y, we0.w, fmaf(ce.z, we1.w, fmaf(ce.w, we2.w, xr1.y))) + f1.y;
                    float pp = tx * (tx > 0.f ? attv.x : att02.x);
                    pp = fmaf(ty, (ty > 0.f ? attv.y : att02.y), pp);
                    pp = fmaf(tz, (tz > 0.f ? attv.z : att02.z), pp);
                    pp = fmaf(tw, (tw > 0.f ? attv.w : att02.w), pp);
                    p[j] = pp;
                } else {
                    p[j] = -INFINITY;   // exp(-inf)=0 -> padding contributes nothing
                    xpk[j] = make_uint2(0u, 0u);
                }
            }
            // 16-lane reduce within each head group
#pragma unroll
            for (int off = 1; off < 16; off <<= 1) {
#pragma unroll
                for (int j = 0; j < EB; j++) p[j] += __shfl_xor(p[j], off);
            }
            // fixed-shift softmax accumulate (no max tracking)
#pragma unroll
            for (int j = 0; j < EB; j++) {
                float wv = __expf(p[j]);
                float2 f0 = __half22float2(*(const __half2*)&xpk[j].x);
                float2 f1 = __half22float2(*(const __half2*)&xpk[j].y);
                acc.x = fmaf(wv, f0.x, acc.x);
                acc.y = fmaf(wv, f0.y, acc.y);
                acc.z = fmaf(wv, f1.x, acc.z);
                acc.w = fmaf(wv, f1.y, acc.w);
                l_run += wv;
            }
        }
        // ---- epilogue: head-mean + BN/bias (precomputed) + ELU + residual
        float inv = (end > beg) ? 1.f / l_run : 0.f;
        float4 o = make_float4(acc.x * inv, acc.y * inv, acc.z * inv, acc.w * inv);
#pragma unroll
        for (int off = 16; off < 64; off <<= 1) {
            o.x += __shfl_xor(o.x, off);
            o.y += __shfl_xor(o.y, off);
            o.z += __shfl_xor(o.z, off);
            o.w += __shfl_xor(o.w, off);
        }
        if (lane < 16) {
            float vx = fmaf(o.x, eA.x, eB4.x);
            float vy = fmaf(o.y, eA.y, eB4.y);
            float vz = fmaf(o.z, eA.z, eB4.z);
            float vw = fmaf(o.w, eA.w, eB4.w);
            vx = vx > 0.f ? vx : expm1f(vx);
            vy = vy > 0.f ? vy : expm1f(vy);
            vz = vz > 0.f ? vz : expm1f(vz);
            vw = vw > 0.f ? vw : expm1f(vw);
            if (hres) {
                float4 r4 = *(const float4*)&hres[((size_t)d << 6) + (lane << 2)];
                vx += r4.x; vy += r4.y; vz += r4.z; vw += r4.w;
            }
            *(float4*)&hout[((size_t)d << 6) + (lane << 2)] = make_float4(vx, vy, vz, vw);
        }
        // ---- roll to prefetched node
        d = dn; beg = begn; end = endn; xrp = xrpn;
    }
}

// ---------------------------------------------------------------- pooling
__global__ __launch_bounds__(256) void pool_kernel(const float* __restrict__ h,
                                                   const int* __restrict__ batch,
                                                   float* __restrict__ pooled,
                                                   int* __restrict__ cnt, int Nn) {
    int idx = blockIdx.x * 256 + threadIdx.x;
    int n = idx >> 6, c = idx & 63;
    if (n < Nn) {
        int g = batch[n];
        atomicAdd(&pooled[(size_t)g * 64 + c], h[(size_t)n * 64 + c]);
        if (c == 0) atomicAdd(&cnt[g], 1);
    }
}

// ---------------------------------------------------------------- MLP head
__global__ __launch_bounds__(64) void head_kernel(const float* __restrict__ pooled,
                                                  const int* __restrict__ cnt,
                                                  const float* __restrict__ Wo1,
                                                  const float* __restrict__ bo1,
                                                  const float* __restrict__ Wo2,
                                                  const float* __restrict__ bo2,
                                                  float* __restrict__ out, int Gg) {
    int g = blockIdx.x;
    int t = threadIdx.x;
    __shared__ float sp[64];
    float c = fmaxf((float)cnt[g], 1.f);
    sp[t] = pooled[(size_t)g * 64 + t] / c;
    __syncthreads();
    float hid = 0.f;
    if (t < 32) {
        hid = bo1[t];
        for (int k = 0; k < 64; k++) hid += sp[k] * Wo1[k * 32 + t];
        hid = hid > 0.f ? hid : expm1f(hid);
        hid *= Wo2[t];
    }
#pragma unroll
    for (int off = 32; off; off >>= 1) hid += __shfl_xor(hid, off);
    if (t == 0) out[g] = hid + bo2[0];
}

extern "C" void kernel_launch(void* const* d_in, const int* in_sizes, int n_in,
                              void* d_out, int out_size, void* d_ws, size_t ws_size,
                              hipStream_t stream) {
    const float* x   = (const float*)d_in[0];
    const int*   ei  = (const int*)d_in[1];
    const int*   bat = (const int*)d_in[2];
    const float* ea  = (const float*)d_in[3];
    const float* W0l = (const float*)d_in[4];
    const float* b0l = (const float*)d_in[5];
    const float* W0r = (const float*)d_in[6];
    const float* W0e = (const float*)d_in[7];
    const float* a0  = (const float*)d_in[8];
    const float* c0  = (const float*)d_in[9];
    const float* Wl  = (const float*)d_in[10];
    const float* bl  = (const float*)d_in[11];
    const float* Wr  = (const float*)d_in[12];
    const float* We  = (const float*)d_in[13];
    const float* a   = (const float*)d_in[14];
    const float* cb  = (const float*)d_in[15];
    const float* bng = (const float*)d_in[16];
    const float* bnb = (const float*)d_in[17];
    const float* bnm = (const float*)d_in[18];
    const float* bnv = (const float*)d_in[19];
    const float* Wo1 = (const float*)d_in[20];
    const float* bo1 = (const float*)d_in[21];
    const float* Wo2 = (const float*)d_in[22];
    const float* bo2 = (const float*)d_in[23];

    int Nn = in_sizes[2];
    int Ee = in_sizes[1] / 2;
    int Gg = out_size;
    const int* srcv = ei;
    const int* dstv = ei + Ee;

    char* w = (char*)d_ws;
    auto alloc = [&](size_t bytes) {
        char* p = w;
        w += (bytes + 255) & ~(size_t)255;
        return p;
    };
    __half* xlb    = (__half*)alloc((size_t)Nn * 256 * 2);
    __half* xrb    = (__half*)alloc((size_t)Nn * 256 * 2);
    float*  hbuf   = (float*)alloc((size_t)Nn * 64 * 4);
    int*    deg    = (int*)alloc((size_t)Nn * 4);
    int*    rowptr = (int*)alloc((size_t)(Nn + 1) * 4);
    int*    cursor = (int*)alloc((size_t)Nn * 4);
    float4* csr4   = (float4*)alloc((size_t)Ee * 16);
    float*  pooled = (float*)alloc((size_t)Gg * 64 * 4);
    int*    cnt    = (int*)alloc((size_t)Gg * 4);
    int*    bsum   = (int*)alloc(256 * 4);
    float*  epi    = (float*)alloc(4 * 128 * 4);
    __half* Wp     = (__half*)alloc((size_t)4 * 32768 * 2);

    int nscan = (Nn + SCAN_ELEMS - 1) / SCAN_ELEMS;  // <=256 for Nn<=262144

    // CSR build + weight/epilogue prep
    hipMemsetAsync(deg, 0, (size_t)Nn * 4, stream);
    count_kernel<<<(Ee + 255) / 256, 256, 0, stream>>>(dstv, deg, Ee);
    scan_phase1<<<nscan, 256, 0, stream>>>(deg, bsum, Nn);
    scan_phase2<<<1, 256, 0, stream>>>(bsum, nscan, rowptr, Nn);
    scan_phase3<<<nscan, 256, 0, stream>>>(deg, bsum, rowptr, cursor, Nn);
    scatter_kernel<<<(Ee + 255) / 256, 256, 0, stream>>>(srcv, dstv, ea, cursor, csr4, Ee);
    bnprep_kernel<<<1, 256, 0, stream>>>(c0, cb, bng, bnb, bnm, bnv, epi);
    wprep_kernel<<<64, 256, 0, stream>>>(W0l, W0r, Wl, Wr, Wp);

    int gatg = 2048;   // persistent: 2048 blocks x 4 waves = 8192 waves
    int gemg = (Nn + 31) / 32;

    // layer 0 (K=9)
    gemm2_mfma_kernel<9><<<gemg, 256, 0, stream>>>(x, Wp, b0l, xlb, xrb, Nn);
    gat_kernel<<<gatg, 256, 0, stream>>>(xlb, xrb, W0e, a0, epi,
                                         rowptr, csr4, hbuf, nullptr, Nn);
    // 3 residual layers (K=64)
    for (int i = 0; i < 3; i++) {
        gemm2_mfma_kernel<64><<<gemg, 256, 0, stream>>>(
            hbuf, Wp + (size_t)(i + 1) * 32768, bl + (size_t)i * 256, xlb, xrb, Nn);
        gat_kernel<<<gatg, 256, 0, stream>>>(
            xlb, xrb, We + (size_t)i * 768, a + (size_t)i * 256, epi + (size_t)(i + 1) * 128,
            rowptr, csr4, hbuf, hbuf, Nn);
    }

    // global mean pool + head
    hipMemsetAsync(pooled, 0, (size_t)Gg * 64 * 4, stream);
    hipMemsetAsync(cnt, 0, (size_t)Gg * 4, stream);
    pool_kernel<<<((size_t)Nn * 64 + 255) / 256, 256, 0, stream>>>(hbuf, bat, pooled, cnt, Nn);
    head_kernel<<<Gg, 64, 0, stream>>>(pooled, cnt, Wo1, bo1, Wo2, bo2, (float*)d_out, Gg);
}

// Round 10
// 493.631 us; speedup vs baseline: 1.7382x; 1.1176x over previous
//
#include <hip/hip_runtime.h>
#include <hip/hip_fp16.h>
#include <math.h>

typedef _Float16 h8 __attribute__((ext_vector_type(8)));
typedef float f4 __attribute__((ext_vector_type(4)));

// ---------------------------------------------------------------- CSR build
__global__ __launch_bounds__(256) void count_kernel(const int* __restrict__ dst,
                                                    int* __restrict__ deg, int E) {
    int e = blockIdx.x * 256 + threadIdx.x;
    if (e < E) atomicAdd(&deg[dst[e]], 1);
}

#define SCAN_TPB 256
#define SCAN_VPT 4
#define SCAN_ELEMS (SCAN_TPB * SCAN_VPT)  // 1024

__global__ __launch_bounds__(256) void scan_phase1(const int* __restrict__ deg,
                                                   int* __restrict__ bsum, int n) {
    __shared__ int sh[SCAN_TPB];
    int base = blockIdx.x * SCAN_ELEMS + threadIdx.x * SCAN_VPT;
    int s = 0;
#pragma unroll
    for (int j = 0; j < SCAN_VPT; j++) { int i = base + j; if (i < n) s += deg[i]; }
    sh[threadIdx.x] = s;
    __syncthreads();
    for (int off = 128; off; off >>= 1) {
        if (threadIdx.x < (unsigned)off) sh[threadIdx.x] += sh[threadIdx.x + off];
        __syncthreads();
    }
    if (threadIdx.x == 0) bsum[blockIdx.x] = sh[0];
}

__global__ __launch_bounds__(256) void scan_phase2(int* __restrict__ bsum, int nb,
                                                   int* __restrict__ rowptr, int n) {
    __shared__ int sh[256];
    int v = (threadIdx.x < (unsigned)nb) ? bsum[threadIdx.x] : 0;
    sh[threadIdx.x] = v;
    __syncthreads();
    for (int off = 1; off < 256; off <<= 1) {
        int t = (threadIdx.x >= (unsigned)off) ? sh[threadIdx.x - off] : 0;
        __syncthreads();
        sh[threadIdx.x] += t;
        __syncthreads();
    }
    if (threadIdx.x < (unsigned)nb) bsum[threadIdx.x] = sh[threadIdx.x] - v;  // exclusive
    if (threadIdx.x == 0) rowptr[n] = sh[255];                                // total
}

__global__ __launch_bounds__(256) void scan_phase3(const int* __restrict__ deg,
                                                   const int* __restrict__ bsum,
                                                   int* __restrict__ rowptr,
                                                   int* __restrict__ cursor, int n) {
    __shared__ int sh[SCAN_TPB];
    int tid = threadIdx.x;
    int base = blockIdx.x * SCAN_ELEMS + tid * SCAN_VPT;
    int v[SCAN_VPT];
    int s = 0;
#pragma unroll
    for (int j = 0; j < SCAN_VPT; j++) { int i = base + j; v[j] = (i < n) ? deg[i] : 0; s += v[j]; }
    sh[tid] = s;
    __syncthreads();
    for (int off = 1; off < SCAN_TPB; off <<= 1) {
        int t = (tid >= off) ? sh[tid - off] : 0;
        __syncthreads();
        sh[tid] += t;
        __syncthreads();
    }
    int ex = sh[tid] - s + bsum[blockIdx.x];
#pragma unroll
    for (int j = 0; j < SCAN_VPT; j++) {
        int i = base + j;
        if (i < n) { rowptr[i] = ex; cursor[i] = ex; ex += v[j]; }
    }
}

// CSR record: {src_as_float_bits, ea0, ea1, ea2} — one s_load_dwordx4 per edge
__global__ __launch_bounds__(256) void scatter_kernel(const int* __restrict__ src,
                                                      const int* __restrict__ dst,
                                                      const float* __restrict__ ea,
                                                      int* __restrict__ cursor,
                                                      float4* __restrict__ csr4, int E) {
    int e = blockIdx.x * 256 + threadIdx.x;
    if (e < E) {
        int d = dst[e];
        int pos = atomicAdd(&cursor[d], 1);
        size_t eb3 = (size_t)e * 3;
        csr4[pos] = make_float4(__int_as_float(src[e]), ea[eb3], ea[eb3 + 1], ea[eb3 + 2]);
    }
}

// ------------- epilogue constants: A = 0.25*g*rsqrt(v+eps); B = (bias-m)*s+b
__global__ __launch_bounds__(256) void bnprep_kernel(const float* __restrict__ c0,
                                                     const float* __restrict__ cb,   // [3][64]
                                                     const float* __restrict__ bng,
                                                     const float* __restrict__ bnb,
                                                     const float* __restrict__ bnm,
                                                     const float* __restrict__ bnv,
                                                     float* __restrict__ epi) {      // [4][2][64]
    int t = threadIdx.x;           // exactly 256 = 4 layers x 64 channels
    int l = t >> 6, c = t & 63;
    float s = bng[l * 64 + c] * rsqrtf(bnv[l * 64 + c] + 1e-5f);
    float bias = (l == 0) ? c0[c] : cb[(l - 1) * 64 + c];
    epi[l * 128 + c] = 0.25f * s;
    epi[l * 128 + 64 + c] = (bias - bnm[l * 64 + c]) * s + bnb[l * 64 + c];
}

// ------------- weight prep: pack Wl|Wr (fp16, zero-padded) into MFMA A-frag
// order. Wp[layer][((gct*2 + ks)*64 + lane)*8 + j] = W_side[k][c], where
// side = (gct<16 ? Wl : Wr), c = (gct&15)*16 + (lane&15),
// k = ks*32 + (lane>>4)*8 + j (0 if k >= K). Layer stride 32768 halfs.
__global__ __launch_bounds__(256) void wprep_kernel(const float* __restrict__ W0l,
                                                    const float* __restrict__ W0r,
                                                    const float* __restrict__ Wl,
                                                    const float* __restrict__ Wr,
                                                    __half* __restrict__ Wp) {
    int t = blockIdx.x * 256 + threadIdx.x;   // 4 layers * 4096
    int layer = t >> 12;
    int r = t & 4095;
    int lane = r & 63;
    int ks = (r >> 6) & 1;
    int gct = r >> 7;                          // 0..31
    int K = (layer == 0) ? 9 : 64;
    const float* Wsrc;
    if (layer == 0) Wsrc = (gct < 16) ? W0l : W0r;
    else            Wsrc = ((gct < 16) ? Wl : Wr) + (size_t)(layer - 1) * 64 * 256;
    int cl = ((gct & 15) << 4) + (lane & 15);
    int k0 = (ks << 5) + ((lane >> 4) << 3);
    __half vals[8] __attribute__((aligned(16)));
#pragma unroll
    for (int j = 0; j < 8; j++) {
        int k = k0 + j;
        vals[j] = __float2half_rn((k < K) ? Wsrc[(size_t)k * 256 + cl] : 0.f);
    }
    *(uint4*)(Wp + (size_t)t * 8) = *(const uint4*)vals;
}

// ----------------- MFMA gemm2: xl = fp16(x@Wl+bl), xr = fp16(x@Wr).
// B (x rows) staged cooperatively into padded LDS with coalesced float4
// loads; fragments read back via ds_read_b128 (stride 68 words -> 2-way
// bank alias = free). A = packed W^T frags (uint4 loads, L2-hot). D frag:
// node = lane&15, col = (lane>>4)*4 + reg -> one 8B store per tile.
template <int K>
__global__ __launch_bounds__(256) void gemm2_mfma_kernel(const float* __restrict__ xin,
                                                         const __half* __restrict__ Wp,
                                                         const float* __restrict__ bl,
                                                         __half* __restrict__ xl,
                                                         __half* __restrict__ xr, int Nn) {
    constexpr int NKS = (K > 32) ? 2 : 1;
    constexpr int KP = NKS * 32;                 // padded K (32 or 64)
    __shared__ __align__(16) float shx[32][KP + 4];
    int tid = threadIdx.x;
    int lane = tid & 63;
    int wv = tid >> 6;           // 0..3
    int nb = blockIdx.x * 32;
    int l15 = lane & 15;
    int lg = lane >> 4;          // 0..3

    // ---- stage B into LDS (coalesced)
    if (K != KP) {
        for (int q = tid; q < 32 * KP; q += 256) shx[q / KP][q % KP] = 0.f;
        __syncthreads();
    }
    if (K == 64) {
        for (int q = tid; q < 32 * 16; q += 256) {   // 512 float4
            int r = q >> 4, c4 = q & 15;
            int node = nb + r;
            float4 v = (node < Nn) ? *(const float4*)(xin + (size_t)node * 64 + c4 * 4)
                                   : make_float4(0.f, 0.f, 0.f, 0.f);
            *(float4*)&shx[r][c4 * 4] = v;
        }
    } else {
        for (int q = tid; q < 32 * K; q += 256) {
            int r = q / K, c = q - r * K;
            int node = nb + r;
            shx[r][c] = (node < Nn) ? xin[(size_t)node * K + c] : 0.f;
        }
    }
    __syncthreads();

    // A fragments (weights), resident: 8 col-tiles x NKS
    h8 afr[8][NKS];
#pragma unroll
    for (int i = 0; i < 8; i++) {
        int gct = wv * 8 + i;
#pragma unroll
        for (int ks = 0; ks < NKS; ks++)
            afr[i][ks] = *(const h8*)(Wp + (((size_t)(gct * 2 + ks)) * 64 + lane) * 8);
    }
    // B fragments from LDS -> fp16
    h8 bfr[2][NKS];
#pragma unroll
    for (int nt = 0; nt < 2; nt++) {
        int row = nt * 16 + l15;
#pragma unroll
        for (int ks = 0; ks < NKS; ks++) {
            int k0 = ks * 32 + lg * 8;
            float4 f0 = *(const float4*)&shx[row][k0];
            float4 f1 = *(const float4*)&shx[row][k0 + 4];
            h8 b;
            b[0] = (_Float16)f0.x; b[1] = (_Float16)f0.y;
            b[2] = (_Float16)f0.z; b[3] = (_Float16)f0.w;
            b[4] = (_Float16)f1.x; b[5] = (_Float16)f1.y;
            b[6] = (_Float16)f1.z; b[7] = (_Float16)f1.w;
            bfr[nt][ks] = b;
        }
    }
    // accumulators, init with bias on the xl side
    f4 acc[8][2];
#pragma unroll
    for (int i = 0; i < 8; i++) {
        int gct = wv * 8 + i;
        f4 ini;
        if (gct < 16) {
            float4 b4 = *(const float4*)(bl + (gct << 4) + (lg << 2));
            ini[0] = b4.x; ini[1] = b4.y; ini[2] = b4.z; ini[3] = b4.w;
        } else {
            ini[0] = 0.f; ini[1] = 0.f; ini[2] = 0.f; ini[3] = 0.f;
        }
        acc[i][0] = ini;
        acc[i][1] = ini;
    }
    // matrix core
#pragma unroll
    for (int i = 0; i < 8; i++)
#pragma unroll
        for (int nt = 0; nt < 2; nt++)
#pragma unroll
            for (int ks = 0; ks < NKS; ks++)
                acc[i][nt] = __builtin_amdgcn_mfma_f32_16x16x32_f16(
                    afr[i][ks], bfr[nt][ks], acc[i][nt], 0, 0, 0);
    // store: 4 consecutive cols per lane -> uint2
#pragma unroll
    for (int i = 0; i < 8; i++) {
        int gct = wv * 8 + i;
        __half* outp = (gct < 16) ? xl : xr;
        int cl = ((gct & 15) << 4) + (lg << 2);
#pragma unroll
        for (int nt = 0; nt < 2; nt++) {
            int node = nb + nt * 16 + l15;
            if (node < Nn) {
                __half h4[4] __attribute__((aligned(8)));
                h4[0] = __float2half_rn(acc[i][nt][0]);
                h4[1] = __float2half_rn(acc[i][nt][1]);
                h4[2] = __float2half_rn(acc[i][nt][2]);
                h4[3] = __float2half_rn(acc[i][nt][3]);
                *(uint2*)(outp + (size_t)node * 256 + cl) = *(const uint2*)h4;
            }
        }
    }
}

// --------------------------- fused GATv2: persistent wave-per-node with
// register double-buffered edge batches (A/B, EB=6 each): batch i+1's csr4
// s_loads + xl gathers issue BEFORE batch i's compute, so the gather wait
// hides under ~150 VALU ops. Named buffers only (no runtime-indexed arrays).
#define EB 6

#define GISSUE(S, ibase)                                                               \
    {                                                                                  \
        _Pragma("unroll") for (int j = 0; j < EB; j++) {                               \
            int idx = (ibase) + j;                                                     \
            if (idx < end) {                                                           \
                float4 ce = csr4[idx]; /* uniform -> s_load_dwordx4 */                 \
                cey##S[j] = ce.y; cez##S[j] = ce.z; cew##S[j] = ce.w;                  \
                int sn = __float_as_int(ce.x);                                         \
                xpk##S[j] = *(const uint2*)(xl + ((size_t)sn << 8) + (lane << 2));     \
            } else {                                                                   \
                cey##S[j] = 0.f; cez##S[j] = 0.f; cew##S[j] = 0.f;                     \
                xpk##S[j] = make_uint2(0u, 0u);                                        \
            }                                                                          \
        }                                                                              \
    }

#define GCOMPUTE(S, ibase)                                                             \
    {                                                                                  \
        float p[EB];                                                                   \
        _Pragma("unroll") for (int j = 0; j < EB; j++) {                               \
            int idx = (ibase) + j;                                                     \
            if (idx < end) {                                                           \
                float2 f0 = __half22float2(*(const __half2*)&xpk##S[j].x);             \
                float2 f1 = __half22float2(*(const __half2*)&xpk##S[j].y);             \
                float tx = fmaf(cey##S[j], we0.x,                                      \
                             fmaf(cez##S[j], we1.x, fmaf(cew##S[j], we2.x, xr0.x)))    \
                           + f0.x;                                                     \
                float ty = fmaf(cey##S[j], we0.y,                                      \
                             fmaf(cez##S[j], we1.y, fmaf(cew##S[j], we2.y, xr0.y)))    \
                           + f0.y;                                                     \
                float tz = fmaf(cey##S[j], we0.z,                                      \
                             fmaf(cez##S[j], we1.z, fmaf(cew##S[j], we2.z, xr1.x)))    \
                           + f1.x;                                                     \
                float tw = fmaf(cey##S[j], we0.w,                                      \
                             fmaf(cez##S[j], we1.w, fmaf(cew##S[j], we2.w, xr1.y)))    \
                           + f1.y;                                                     \
                float pp = tx * (tx > 0.f ? attv.x : att02.x);                         \
                pp = fmaf(ty, (ty > 0.f ? attv.y : att02.y), pp);                      \
                pp = fmaf(tz, (tz > 0.f ? attv.z : att02.z), pp);                      \
                pp = fmaf(tw, (tw > 0.f ? attv.w : att02.w), pp);                      \
                p[j] = pp;                                                             \
            } else p[j] = -INFINITY;                                                   \
        }                                                                              \
        _Pragma("unroll") for (int off = 1; off < 16; off <<= 1) {                     \
            _Pragma("unroll") for (int j = 0; j < EB; j++) p[j] += __shfl_xor(p[j], off); \
        }                                                                              \
        _Pragma("unroll") for (int j = 0; j < EB; j++) {                               \
            float wv2 = __expf(p[j]);                                                  \
            float2 f0 = __half22float2(*(const __half2*)&xpk##S[j].x);                 \
            float2 f1 = __half22float2(*(const __half2*)&xpk##S[j].y);                 \
            acc.x = fmaf(wv2, f0.x, acc.x);                                            \
            acc.y = fmaf(wv2, f0.y, acc.y);                                            \
            acc.z = fmaf(wv2, f1.x, acc.z);                                            \
            acc.w = fmaf(wv2, f1.y, acc.w);                                            \
            l_run += wv2;                                                              \
        }                                                                              \
    }

__global__ __launch_bounds__(256) void gat_kernel(const __half* __restrict__ xl,
                                                  const __half* __restrict__ xr,
                                                  const float* __restrict__ We,   // [3,256]
                                                  const float* __restrict__ att,  // [256]
                                                  const float* __restrict__ epi,  // [2][64]
                                                  const int* __restrict__ rowptr,
                                                  const float4* __restrict__ csr4,
                                                  float* __restrict__ hout,       // [N,64]
                                                  const float* __restrict__ hres, // [N,64] or null
                                                  int Nn) {
    int tid = threadIdx.x;
    int lane = tid & 63;
    int w = __builtin_amdgcn_readfirstlane(tid >> 6);   // scalar wave-in-block
    int wave = blockIdx.x * 4 + w;                      // scalar
    int nwaves = gridDim.x * 4;

    float4 we0 = *(const float4*)&We[lane * 4];
    float4 we1 = *(const float4*)&We[256 + lane * 4];
    float4 we2 = *(const float4*)&We[512 + lane * 4];
    float4 attv = *(const float4*)&att[lane * 4];
    float4 att02 = make_float4(0.2f * attv.x, 0.2f * attv.y, 0.2f * attv.z, 0.2f * attv.w);
    float4 eA = *(const float4*)&epi[(lane & 15) * 4];
    float4 eB4 = *(const float4*)&epi[64 + (lane & 15) * 4];

    int d = wave;
    if (d >= Nn) return;
    int beg = rowptr[d];            // scalar loads
    int end = rowptr[d + 1];
    uint2 xrp = *(const uint2*)(xr + ((size_t)d << 8) + (lane << 2));

    uint2 xpkA[EB], xpkB[EB];
    float ceyA[EB], cezA[EB], cewA[EB], ceyB[EB], cezB[EB], cewB[EB];

    while (d < Nn) {
        // ---- prefetch next node's meta (SGPR + 2 VGPR), consumed at roll
        int dn = d + nwaves;
        int begn = 0, endn = 0;
        uint2 xrpn = make_uint2(0u, 0u);
        if (dn < Nn) {
            begn = rowptr[dn];
            endn = rowptr[dn + 1];
            xrpn = *(const uint2*)(xr + ((size_t)dn << 8) + (lane << 2));
        }
        // ---- current node
        float2 xr0 = __half22float2(*(const __half2*)&xrp.x);
        float2 xr1 = __half22float2(*(const __half2*)&xrp.y);

        float l_run = 0.f;
        float4 acc = make_float4(0.f, 0.f, 0.f, 0.f);

        int i = beg;
        if (i < end) {
            GISSUE(A, i);
            for (;;) {
                int nx = i + EB;
                if (nx < end) GISSUE(B, nx);
                GCOMPUTE(A, i);
                i = nx;
                if (i >= end) break;
                nx = i + EB;
                if (nx < end) GISSUE(A, nx);
                GCOMPUTE(B, i);
                i = nx;
                if (i >= end) break;
            }
        }
        // ---- epilogue: head-mean + BN/bias (precomputed) + ELU + residual
        float inv = (end > beg) ? 1.f / l_run : 0.f;
        float4 o = make_float4(acc.x * inv, acc.y * inv, acc.z * inv, acc.w * inv);
#pragma unroll
        for (int off = 16; off < 64; off <<= 1) {
            o.x += __shfl_xor(o.x, off);
            o.y += __shfl_xor(o.y, off);
            o.z += __shfl_xor(o.z, off);
            o.w += __shfl_xor(o.w, off);
        }
        if (lane < 16) {
            float vx = fmaf(o.x, eA.x, eB4.x);
            float vy = fmaf(o.y, eA.y, eB4.y);
            float vz = fmaf(o.z, eA.z, eB4.z);
            float vw = fmaf(o.w, eA.w, eB4.w);
            vx = vx > 0.f ? vx : expm1f(vx);
            vy = vy > 0.f ? vy : expm1f(vy);
            vz = vz > 0.f ? vz : expm1f(vz);
            vw = vw > 0.f ? vw : expm1f(vw);
            if (hres) {
                float4 r4 = *(const float4*)&hres[((size_t)d << 6) + (lane << 2)];
                vx += r4.x; vy += r4.y; vz += r4.z; vw += r4.w;
            }
            *(float4*)&hout[((size_t)d << 6) + (lane << 2)] = make_float4(vx, vy, vz, vw);
        }
        // ---- roll to prefetched node
        d = dn; beg = begn; end = endn; xrp = xrpn;
    }
}

// ---------------------------------------------------------------- pooling
__global__ __launch_bounds__(256) void pool_kernel(const float* __restrict__ h,
                                                   const int* __restrict__ batch,
                                                   float* __restrict__ pooled,
                                                   int* __restrict__ cnt, int Nn) {
    int idx = blockIdx.x * 256 + threadIdx.x;
    int n = idx >> 6, c = idx & 63;
    if (n < Nn) {
        int g = batch[n];
        atomicAdd(&pooled[(size_t)g * 64 + c], h[(size_t)n * 64 + c]);
        if (c == 0) atomicAdd(&cnt[g], 1);
    }
}

// ---------------------------------------------------------------- MLP head
__global__ __launch_bounds__(64) void head_kernel(const float* __restrict__ pooled,
                                                  const int* __restrict__ cnt,
                                                  const float* __restrict__ Wo1,
                                                  const float* __restrict__ bo1,
                                                  const float* __restrict__ Wo2,
                                                  const float* __restrict__ bo2,
                                                  float* __restrict__ out, int Gg) {
    int g = blockIdx.x;
    int t = threadIdx.x;
    __shared__ float sp[64];
    float c = fmaxf((float)cnt[g], 1.f);
    sp[t] = pooled[(size_t)g * 64 + t] / c;
    __syncthreads();
    float hid = 0.f;
    if (t < 32) {
        hid = bo1[t];
        for (int k = 0; k < 64; k++) hid += sp[k] * Wo1[k * 32 + t];
        hid = hid > 0.f ? hid : expm1f(hid);
        hid *= Wo2[t];
    }
#pragma unroll
    for (int off = 32; off; off >>= 1) hid += __shfl_xor(hid, off);
    if (t == 0) out[g] = hid + bo2[0];
}

extern "C" void kernel_launch(void* const* d_in, const int* in_sizes, int n_in,
                              void* d_out, int out_size, void* d_ws, size_t ws_size,
                              hipStream_t stream) {
    const float* x   = (const float*)d_in[0];
    const int*   ei  = (const int*)d_in[1];
    const int*   bat = (const int*)d_in[2];
    const float* ea  = (const float*)d_in[3];
    const float* W0l = (const float*)d_in[4];
    const float* b0l = (const float*)d_in[5];
    const float* W0r = (const float*)d_in[6];
    const float* W0e = (const float*)d_in[7];
    const float* a0  = (const float*)d_in[8];
    const float* c0  = (const float*)d_in[9];
    const float* Wl  = (const float*)d_in[10];
    const float* bl  = (const float*)d_in[11];
    const float* Wr  = (const float*)d_in[12];
    const float* We  = (const float*)d_in[13];
    const float* a   = (const float*)d_in[14];
    const float* cb  = (const float*)d_in[15];
    const float* bng = (const float*)d_in[16];
    const float* bnb = (const float*)d_in[17];
    const float* bnm = (const float*)d_in[18];
    const float* bnv = (const float*)d_in[19];
    const float* Wo1 = (const float*)d_in[20];
    const float* bo1 = (const float*)d_in[21];
    const float* Wo2 = (const float*)d_in[22];
    const float* bo2 = (const float*)d_in[23];

    int Nn = in_sizes[2];
    int Ee = in_sizes[1] / 2;
    int Gg = out_size;
    const int* srcv = ei;
    const int* dstv = ei + Ee;

    char* w = (char*)d_ws;
    auto alloc = [&](size_t bytes) {
        char* p = w;
        w += (bytes + 255) & ~(size_t)255;
        return p;
    };
    __half* xlb    = (__half*)alloc((size_t)Nn * 256 * 2);
    __half* xrb    = (__half*)alloc((size_t)Nn * 256 * 2);
    float*  hbuf   = (float*)alloc((size_t)Nn * 64 * 4);
    int*    deg    = (int*)alloc((size_t)Nn * 4);
    int*    rowptr = (int*)alloc((size_t)(Nn + 1) * 4);
    int*    cursor = (int*)alloc((size_t)Nn * 4);
    float4* csr4   = (float4*)alloc((size_t)Ee * 16);
    float*  pooled = (float*)alloc((size_t)Gg * 64 * 4);
    int*    cnt    = (int*)alloc((size_t)Gg * 4);
    int*    bsum   = (int*)alloc(256 * 4);
    float*  epi    = (float*)alloc(4 * 128 * 4);
    __half* Wp     = (__half*)alloc((size_t)4 * 32768 * 2);

    int nscan = (Nn + SCAN_ELEMS - 1) / SCAN_ELEMS;  // <=256 for Nn<=262144

    // CSR build + weight/epilogue prep
    hipMemsetAsync(deg, 0, (size_t)Nn * 4, stream);
    count_kernel<<<(Ee + 255) / 256, 256, 0, stream>>>(dstv, deg, Ee);
    scan_phase1<<<nscan, 256, 0, stream>>>(deg, bsum, Nn);
    scan_phase2<<<1, 256, 0, stream>>>(bsum, nscan, rowptr, Nn);
    scan_phase3<<<nscan, 256, 0, stream>>>(deg, bsum, rowptr, cursor, Nn);
    scatter_kernel<<<(Ee + 255) / 256, 256, 0, stream>>>(srcv, dstv, ea, cursor, csr4, Ee);
    bnprep_kernel<<<1, 256, 0, stream>>>(c0, cb, bng, bnb, bnm, bnv, epi);
    wprep_kernel<<<64, 256, 0, stream>>>(W0l, W0r, Wl, Wr, Wp);

    int gatg = 2048;   // persistent: 2048 blocks x 4 waves = 8192 waves
    int gemg = (Nn + 31) / 32;

    // layer 0 (K=9)
    gemm2_mfma_kernel<9><<<gemg, 256, 0, stream>>>(x, Wp, b0l, xlb, xrb, Nn);
    gat_kernel<<<gatg, 256, 0, stream>>>(xlb, xrb, W0e, a0, epi,
                                         rowptr, csr4, hbuf, nullptr, Nn);
    // 3 residual layers (K=64)
    for (int i = 0; i < 3; i++) {
        gemm2_mfma_kernel<64><<<gemg, 256, 0, stream>>>(
            hbuf, Wp + (size_t)(i + 1) * 32768, bl + (size_t)i * 256, xlb, xrb, Nn);
        gat_kernel<<<gatg, 256, 0, stream>>>(
            xlb, xrb, We + (size_t)i * 768, a + (size_t)i * 256, epi + (size_t)(i + 1) * 128,
            rowptr, csr4, hbuf, hbuf, Nn);
    }

    // global mean pool + head
    hipMemsetAsync(pooled, 0, (size_t)Gg * 64 * 4, stream);
    hipMemsetAsync(cnt, 0, (size_t)Gg * 4, stream);
    pool_kernel<<<((size_t)Nn * 64 + 255) / 256, 256, 0, stream>>>(hbuf, bat, pooled, cnt, Nn);
    head_kernel<<<Gg, 64, 0, stream>>>(pooled, cnt, Wo1, bo1, Wo2, bo2, (float*)d_out, Gg);
}

// Round 11
// 425.824 us; speedup vs baseline: 2.0150x; 1.1592x over previous
//
#include <hip/hip_runtime.h>
#include <hip/hip_fp16.h>
#include <math.h>

typedef _Float16 h8 __attribute__((ext_vector_type(8)));
typedef float f4 __attribute__((ext_vector_type(4)));

// ---------------------------------------------------------------- CSR build
__global__ __launch_bounds__(256) void count_kernel(const int* __restrict__ dst,
                                                    int* __restrict__ deg, int E) {
    int e = blockIdx.x * 256 + threadIdx.x;
    if (e < E) atomicAdd(&deg[dst[e]], 1);
}

#define SCAN_TPB 256
#define SCAN_VPT 4
#define SCAN_ELEMS (SCAN_TPB * SCAN_VPT)  // 1024

__global__ __launch_bounds__(256) void scan_phase1(const int* __restrict__ deg,
                                                   int* __restrict__ bsum, int n) {
    __shared__ int sh[SCAN_TPB];
    int base = blockIdx.x * SCAN_ELEMS + threadIdx.x * SCAN_VPT;
    int s = 0;
#pragma unroll
    for (int j = 0; j < SCAN_VPT; j++) { int i = base + j; if (i < n) s += deg[i]; }
    sh[threadIdx.x] = s;
    __syncthreads();
    for (int off = 128; off; off >>= 1) {
        if (threadIdx.x < (unsigned)off) sh[threadIdx.x] += sh[threadIdx.x + off];
        __syncthreads();
    }
    if (threadIdx.x == 0) bsum[blockIdx.x] = sh[0];
}

__global__ __launch_bounds__(256) void scan_phase2(int* __restrict__ bsum, int nb,
                                                   int* __restrict__ rowptr, int n) {
    __shared__ int sh[256];
    int v = (threadIdx.x < (unsigned)nb) ? bsum[threadIdx.x] : 0;
    sh[threadIdx.x] = v;
    __syncthreads();
    for (int off = 1; off < 256; off <<= 1) {
        int t = (threadIdx.x >= (unsigned)off) ? sh[threadIdx.x - off] : 0;
        __syncthreads();
        sh[threadIdx.x] += t;
        __syncthreads();
    }
    if (threadIdx.x < (unsigned)nb) bsum[threadIdx.x] = sh[threadIdx.x] - v;  // exclusive
    if (threadIdx.x == 0) rowptr[n] = sh[255];                                // total
}

__global__ __launch_bounds__(256) void scan_phase3(const int* __restrict__ deg,
                                                   const int* __restrict__ bsum,
                                                   int* __restrict__ rowptr,
                                                   int* __restrict__ cursor, int n) {
    __shared__ int sh[SCAN_TPB];
    int tid = threadIdx.x;
    int base = blockIdx.x * SCAN_ELEMS + tid * SCAN_VPT;
    int v[SCAN_VPT];
    int s = 0;
#pragma unroll
    for (int j = 0; j < SCAN_VPT; j++) { int i = base + j; v[j] = (i < n) ? deg[i] : 0; s += v[j]; }
    sh[tid] = s;
    __syncthreads();
    for (int off = 1; off < SCAN_TPB; off <<= 1) {
        int t = (tid >= off) ? sh[tid - off] : 0;
        __syncthreads();
        sh[tid] += t;
        __syncthreads();
    }
    int ex = sh[tid] - s + bsum[blockIdx.x];
#pragma unroll
    for (int j = 0; j < SCAN_VPT; j++) {
        int i = base + j;
        if (i < n) { rowptr[i] = ex; cursor[i] = ex; ex += v[j]; }
    }
}

// CSR record: {src_as_float_bits, ea0, ea1, ea2} — one s_load_dwordx4 per edge
__global__ __launch_bounds__(256) void scatter_kernel(const int* __restrict__ src,
                                                      const int* __restrict__ dst,
                                                      const float* __restrict__ ea,
                                                      int* __restrict__ cursor,
                                                      float4* __restrict__ csr4, int E) {
    int e = blockIdx.x * 256 + threadIdx.x;
    if (e < E) {
        int d = dst[e];
        int pos = atomicAdd(&cursor[d], 1);
        size_t eb3 = (size_t)e * 3;
        csr4[pos] = make_float4(__int_as_float(src[e]), ea[eb3], ea[eb3 + 1], ea[eb3 + 2]);
    }
}

// ------------- epilogue constants: A = 0.25*g*rsqrt(v+eps); B = (bias-m)*s+b
__global__ __launch_bounds__(256) void bnprep_kernel(const float* __restrict__ c0,
                                                     const float* __restrict__ cb,   // [3][64]
                                                     const float* __restrict__ bng,
                                                     const float* __restrict__ bnb,
                                                     const float* __restrict__ bnm,
                                                     const float* __restrict__ bnv,
                                                     float* __restrict__ epi) {      // [4][2][64]
    int t = threadIdx.x;           // exactly 256 = 4 layers x 64 channels
    int l = t >> 6, c = t & 63;
    float s = bng[l * 64 + c] * rsqrtf(bnv[l * 64 + c] + 1e-5f);
    float bias = (l == 0) ? c0[c] : cb[(l - 1) * 64 + c];
    epi[l * 128 + c] = 0.25f * s;
    epi[l * 128 + 64 + c] = (bias - bnm[l * 64 + c]) * s + bnb[l * 64 + c];
}

// ------------- group starts from SORTED batch: gstart[g] = first node of g
__global__ __launch_bounds__(256) void gstart_kernel(const int* __restrict__ batch,
                                                     int* __restrict__ gstart,
                                                     int Nn, int Gg) {
    int n = blockIdx.x * 256 + threadIdx.x;
    if (n >= Nn) return;
    int b = batch[n];
    int prev = (n == 0) ? -1 : batch[n - 1];
    for (int g = prev + 1; g <= b; g++) gstart[g] = n;
    if (n == Nn - 1)
        for (int g = b + 1; g <= Gg; g++) gstart[g] = Nn;
}

// ------------- weight prep: pack Wl|Wr (fp16, zero-padded) into MFMA A-frag
// order. Wp[layer][((gct*2 + ks)*64 + lane)*8 + j] = W_side[k][c], where
// side = (gct<16 ? Wl : Wr), c = (gct&15)*16 + (lane&15),
// k = ks*32 + (lane>>4)*8 + j (0 if k >= K). Layer stride 32768 halfs.
__global__ __launch_bounds__(256) void wprep_kernel(const float* __restrict__ W0l,
                                                    const float* __restrict__ W0r,
                                                    const float* __restrict__ Wl,
                                                    const float* __restrict__ Wr,
                                                    __half* __restrict__ Wp) {
    int t = blockIdx.x * 256 + threadIdx.x;   // 4 layers * 4096
    int layer = t >> 12;
    int r = t & 4095;
    int lane = r & 63;
    int ks = (r >> 6) & 1;
    int gct = r >> 7;                          // 0..31
    int K = (layer == 0) ? 9 : 64;
    const float* Wsrc;
    if (layer == 0) Wsrc = (gct < 16) ? W0l : W0r;
    else            Wsrc = ((gct < 16) ? Wl : Wr) + (size_t)(layer - 1) * 64 * 256;
    int cl = ((gct & 15) << 4) + (lane & 15);
    int k0 = (ks << 5) + ((lane >> 4) << 3);
    __half vals[8] __attribute__((aligned(16)));
#pragma unroll
    for (int j = 0; j < 8; j++) {
        int k = k0 + j;
        vals[j] = __float2half_rn((k < K) ? Wsrc[(size_t)k * 256 + cl] : 0.f);
    }
    *(uint4*)(Wp + (size_t)t * 8) = *(const uint4*)vals;
}

// ----------------- MFMA gemm2: xl = fp16(x@Wl+bl), xr = fp16(x@Wr).
// B (x rows) staged cooperatively into padded LDS with coalesced float4
// loads; fragments read back via ds_read_b128. A = packed W^T frags.
// D frag: node = lane&15, col = (lane>>4)*4 + reg -> one 8B store per tile.
template <int K>
__global__ __launch_bounds__(256) void gemm2_mfma_kernel(const float* __restrict__ xin,
                                                         const __half* __restrict__ Wp,
                                                         const float* __restrict__ bl,
                                                         __half* __restrict__ xl,
                                                         __half* __restrict__ xr, int Nn) {
    constexpr int NKS = (K > 32) ? 2 : 1;
    constexpr int KP = NKS * 32;                 // padded K (32 or 64)
    __shared__ __align__(16) float shx[32][KP + 4];
    int tid = threadIdx.x;
    int lane = tid & 63;
    int wv = tid >> 6;           // 0..3
    int nb = blockIdx.x * 32;
    int l15 = lane & 15;
    int lg = lane >> 4;          // 0..3

    // ---- stage B into LDS (coalesced)
    if (K != KP) {
        for (int q = tid; q < 32 * KP; q += 256) shx[q / KP][q % KP] = 0.f;
        __syncthreads();
    }
    if (K == 64) {
        for (int q = tid; q < 32 * 16; q += 256) {   // 512 float4
            int r = q >> 4, c4 = q & 15;
            int node = nb + r;
            float4 v = (node < Nn) ? *(const float4*)(xin + (size_t)node * 64 + c4 * 4)
                                   : make_float4(0.f, 0.f, 0.f, 0.f);
            *(float4*)&shx[r][c4 * 4] = v;
        }
    } else {
        for (int q = tid; q < 32 * K; q += 256) {
            int r = q / K, c = q - r * K;
            int node = nb + r;
            shx[r][c] = (node < Nn) ? xin[(size_t)node * K + c] : 0.f;
        }
    }
    __syncthreads();

    // A fragments (weights), resident: 8 col-tiles x NKS
    h8 afr[8][NKS];
#pragma unroll
    for (int i = 0; i < 8; i++) {
        int gct = wv * 8 + i;
#pragma unroll
        for (int ks = 0; ks < NKS; ks++)
            afr[i][ks] = *(const h8*)(Wp + (((size_t)(gct * 2 + ks)) * 64 + lane) * 8);
    }
    // B fragments from LDS -> fp16
    h8 bfr[2][NKS];
#pragma unroll
    for (int nt = 0; nt < 2; nt++) {
        int row = nt * 16 + l15;
#pragma unroll
        for (int ks = 0; ks < NKS; ks++) {
            int k0 = ks * 32 + lg * 8;
            float4 f0 = *(const float4*)&shx[row][k0];
            float4 f1 = *(const float4*)&shx[row][k0 + 4];
            h8 b;
            b[0] = (_Float16)f0.x; b[1] = (_Float16)f0.y;
            b[2] = (_Float16)f0.z; b[3] = (_Float16)f0.w;
            b[4] = (_Float16)f1.x; b[5] = (_Float16)f1.y;
            b[6] = (_Float16)f1.z; b[7] = (_Float16)f1.w;
            bfr[nt][ks] = b;
        }
    }
    // accumulators, init with bias on the xl side
    f4 acc[8][2];
#pragma unroll
    for (int i = 0; i < 8; i++) {
        int gct = wv * 8 + i;
        f4 ini;
        if (gct < 16) {
            float4 b4 = *(const float4*)(bl + (gct << 4) + (lg << 2));
            ini[0] = b4.x; ini[1] = b4.y; ini[2] = b4.z; ini[3] = b4.w;
        } else {
            ini[0] = 0.f; ini[1] = 0.f; ini[2] = 0.f; ini[3] = 0.f;
        }
        acc[i][0] = ini;
        acc[i][1] = ini;
    }
    // matrix core
#pragma unroll
    for (int i = 0; i < 8; i++)
#pragma unroll
        for (int nt = 0; nt < 2; nt++)
#pragma unroll
            for (int ks = 0; ks < NKS; ks++)
                acc[i][nt] = __builtin_amdgcn_mfma_f32_16x16x32_f16(
                    afr[i][ks], bfr[nt][ks], acc[i][nt], 0, 0, 0);
    // store: 4 consecutive cols per lane -> uint2
#pragma unroll
    for (int i = 0; i < 8; i++) {
        int gct = wv * 8 + i;
        __half* outp = (gct < 16) ? xl : xr;
        int cl = ((gct & 15) << 4) + (lg << 2);
#pragma unroll
        for (int nt = 0; nt < 2; nt++) {
            int node = nb + nt * 16 + l15;
            if (node < Nn) {
                __half h4[4] __attribute__((aligned(8)));
                h4[0] = __float2half_rn(acc[i][nt][0]);
                h4[1] = __float2half_rn(acc[i][nt][1]);
                h4[2] = __float2half_rn(acc[i][nt][2]);
                h4[3] = __float2half_rn(acc[i][nt][3]);
                *(uint2*)(outp + (size_t)node * 256 + cl) = *(const uint2*)h4;
            }
        }
    }
}

// --------------------------- fused GATv2: persistent wave-per-node with
// register double-buffered edge batches (A/B, EB=6 each): batch i+1's csr4
// s_loads + xl gathers issue BEFORE batch i's compute, so the gather wait
// hides under ~150 VALU ops. Named buffers only (no runtime-indexed arrays).
#define EB 6

#define GISSUE(S, ibase)                                                               \
    {                                                                                  \
        _Pragma("unroll") for (int j = 0; j < EB; j++) {                               \
            int idx = (ibase) + j;                                                     \
            if (idx < end) {                                                           \
                float4 ce = csr4[idx]; /* uniform -> s_load_dwordx4 */                 \
                cey##S[j] = ce.y; cez##S[j] = ce.z; cew##S[j] = ce.w;                  \
                int sn = __float_as_int(ce.x);                                         \
                xpk##S[j] = *(const uint2*)(xl + ((size_t)sn << 8) + (lane << 2));     \
            } else {                                                                   \
                cey##S[j] = 0.f; cez##S[j] = 0.f; cew##S[j] = 0.f;                     \
                xpk##S[j] = make_uint2(0u, 0u);                                        \
            }                                                                          \
        }                                                                              \
    }

#define GCOMPUTE(S, ibase)                                                             \
    {                                                                                  \
        float p[EB];                                                                   \
        _Pragma("unroll") for (int j = 0; j < EB; j++) {                               \
            int idx = (ibase) + j;                                                     \
            if (idx < end) {                                                           \
                float2 f0 = __half22float2(*(const __half2*)&xpk##S[j].x);             \
                float2 f1 = __half22float2(*(const __half2*)&xpk##S[j].y);             \
                float tx = fmaf(cey##S[j], we0.x,                                      \
                             fmaf(cez##S[j], we1.x, fmaf(cew##S[j], we2.x, xr0.x)))    \
                           + f0.x;                                                     \
                float ty = fmaf(cey##S[j], we0.y,                                      \
                             fmaf(cez##S[j], we1.y, fmaf(cew##S[j], we2.y, xr0.y)))    \
                           + f0.y;                                                     \
                float tz = fmaf(cey##S[j], we0.z,                                      \
                             fmaf(cez##S[j], we1.z, fmaf(cew##S[j], we2.z, xr1.x)))    \
                           + f1.x;                                                     \
                float tw = fmaf(cey##S[j], we0.w,                                      \
                             fmaf(cez##S[j], we1.w, fmaf(cew##S[j], we2.w, xr1.y)))    \
                           + f1.y;                                                     \
                float pp = tx * (tx > 0.f ? attv.x : att02.x);                         \
                pp = fmaf(ty, (ty > 0.f ? attv.y : att02.y), pp);                      \
                pp = fmaf(tz, (tz > 0.f ? attv.z : att02.z), pp);                      \
                pp = fmaf(tw, (tw > 0.f ? attv.w : att02.w), pp);                      \
                p[j] = pp;                                                             \
            } else p[j] = -INFINITY;                                                   \
        }                                                                              \
        _Pragma("unroll") for (int off = 1; off < 16; off <<= 1) {                     \
            _Pragma("unroll") for (int j = 0; j < EB; j++) p[j] += __shfl_xor(p[j], off); \
        }                                                                              \
        _Pragma("unroll") for (int j = 0; j < EB; j++) {                               \
            float wv2 = __expf(p[j]);                                                  \
            float2 f0 = __half22float2(*(const __half2*)&xpk##S[j].x);                 \
            float2 f1 = __half22float2(*(const __half2*)&xpk##S[j].y);                 \
            acc.x = fmaf(wv2, f0.x, acc.x);                                            \
            acc.y = fmaf(wv2, f0.y, acc.y);                                            \
            acc.z = fmaf(wv2, f1.x, acc.z);                                            \
            acc.w = fmaf(wv2, f1.y, acc.w);                                            \
            l_run += wv2;                                                              \
        }                                                                              \
    }

__global__ __launch_bounds__(256) void gat_kernel(const __half* __restrict__ xl,
                                                  const __half* __restrict__ xr,
                                                  const float* __restrict__ We,   // [3,256]
                                                  const float* __restrict__ att,  // [256]
                                                  const float* __restrict__ epi,  // [2][64]
                                                  const int* __restrict__ rowptr,
                                                  const float4* __restrict__ csr4,
                                                  float* __restrict__ hout,       // [N,64]
                                                  const float* __restrict__ hres, // [N,64] or null
                                                  int Nn) {
    int tid = threadIdx.x;
    int lane = tid & 63;
    int w = __builtin_amdgcn_readfirstlane(tid >> 6);   // scalar wave-in-block
    int wave = blockIdx.x * 4 + w;                      // scalar
    int nwaves = gridDim.x * 4;

    float4 we0 = *(const float4*)&We[lane * 4];
    float4 we1 = *(const float4*)&We[256 + lane * 4];
    float4 we2 = *(const float4*)&We[512 + lane * 4];
    float4 attv = *(const float4*)&att[lane * 4];
    float4 att02 = make_float4(0.2f * attv.x, 0.2f * attv.y, 0.2f * attv.z, 0.2f * attv.w);
    float4 eA = *(const float4*)&epi[(lane & 15) * 4];
    float4 eB4 = *(const float4*)&epi[64 + (lane & 15) * 4];

    int d = wave;
    if (d >= Nn) return;
    int beg = rowptr[d];            // scalar loads
    int end = rowptr[d + 1];
    uint2 xrp = *(const uint2*)(xr + ((size_t)d << 8) + (lane << 2));

    uint2 xpkA[EB], xpkB[EB];
    float ceyA[EB], cezA[EB], cewA[EB], ceyB[EB], cezB[EB], cewB[EB];

    while (d < Nn) {
        // ---- prefetch next node's meta (SGPR + 2 VGPR), consumed at roll
        int dn = d + nwaves;
        int begn = 0, endn = 0;
        uint2 xrpn = make_uint2(0u, 0u);
        if (dn < Nn) {
            begn = rowptr[dn];
            endn = rowptr[dn + 1];
            xrpn = *(const uint2*)(xr + ((size_t)dn << 8) + (lane << 2));
        }
        // ---- current node
        float2 xr0 = __half22float2(*(const __half2*)&xrp.x);
        float2 xr1 = __half22float2(*(const __half2*)&xrp.y);

        float l_run = 0.f;
        float4 acc = make_float4(0.f, 0.f, 0.f, 0.f);

        int i = beg;
        if (i < end) {
            GISSUE(A, i);
            for (;;) {
                int nx = i + EB;
                if (nx < end) GISSUE(B, nx);
                GCOMPUTE(A, i);
                i = nx;
                if (i >= end) break;
                nx = i + EB;
                if (nx < end) GISSUE(A, nx);
                GCOMPUTE(B, i);
                i = nx;
                if (i >= end) break;
            }
        }
        // ---- epilogue: head-mean + BN/bias (precomputed) + ELU + residual
        float inv = (end > beg) ? 1.f / l_run : 0.f;
        float4 o = make_float4(acc.x * inv, acc.y * inv, acc.z * inv, acc.w * inv);
#pragma unroll
        for (int off = 16; off < 64; off <<= 1) {
            o.x += __shfl_xor(o.x, off);
            o.y += __shfl_xor(o.y, off);
            o.z += __shfl_xor(o.z, off);
            o.w += __shfl_xor(o.w, off);
        }
        if (lane < 16) {
            float vx = fmaf(o.x, eA.x, eB4.x);
            float vy = fmaf(o.y, eA.y, eB4.y);
            float vz = fmaf(o.z, eA.z, eB4.z);
            float vw = fmaf(o.w, eA.w, eB4.w);
            vx = vx > 0.f ? vx : expm1f(vx);
            vy = vy > 0.f ? vy : expm1f(vy);
            vz = vz > 0.f ? vz : expm1f(vz);
            vw = vw > 0.f ? vw : expm1f(vw);
            if (hres) {
                float4 r4 = *(const float4*)&hres[((size_t)d << 6) + (lane << 2)];
                vx += r4.x; vy += r4.y; vz += r4.z; vw += r4.w;
            }
            *(float4*)&hout[((size_t)d << 6) + (lane << 2)] = make_float4(vx, vy, vz, vw);
        }
        // ---- roll to prefetched node
        d = dn; beg = begn; end = endn; xrp = xrpn;
    }
}

// -------------------- pooling: one block per graph (batch sorted, no atomics)
__global__ __launch_bounds__(256) void pool_kernel(const float* __restrict__ h,
                                                   const int* __restrict__ gstart,
                                                   float* __restrict__ pooled, int Gg) {
    __shared__ float red[4][64];
    int g = blockIdx.x;
    int tid = threadIdx.x;
    int lane = tid & 63, w = tid >> 6;
    int gs = gstart[g], ge = gstart[g + 1];
    float s = 0.f;
    for (int n = gs + w; n < ge; n += 4) s += h[((size_t)n << 6) + lane];
    red[w][lane] = s;
    __syncthreads();
    if (tid < 64) {
        float tot = red[0][tid] + red[1][tid] + red[2][tid] + red[3][tid];
        float c = fmaxf((float)(ge - gs), 1.f);
        pooled[((size_t)g << 6) + tid] = tot / c;
    }
}

// ---------------------------------------------------------------- MLP head
__global__ __launch_bounds__(64) void head_kernel(const float* __restrict__ pooled,
                                                  const float* __restrict__ Wo1,
                                                  const float* __restrict__ bo1,
                                                  const float* __restrict__ Wo2,
                                                  const float* __restrict__ bo2,
                                                  float* __restrict__ out, int Gg) {
    int g = blockIdx.x;
    int t = threadIdx.x;
    __shared__ float sp[64];
    sp[t] = pooled[(size_t)g * 64 + t];
    __syncthreads();
    float hid = 0.f;
    if (t < 32) {
        hid = bo1[t];
        for (int k = 0; k < 64; k++) hid += sp[k] * Wo1[k * 32 + t];
        hid = hid > 0.f ? hid : expm1f(hid);
        hid *= Wo2[t];
    }
#pragma unroll
    for (int off = 32; off; off >>= 1) hid += __shfl_xor(hid, off);
    if (t == 0) out[g] = hid + bo2[0];
}

extern "C" void kernel_launch(void* const* d_in, const int* in_sizes, int n_in,
                              void* d_out, int out_size, void* d_ws, size_t ws_size,
                              hipStream_t stream) {
    const float* x   = (const float*)d_in[0];
    const int*   ei  = (const int*)d_in[1];
    const int*   bat = (const int*)d_in[2];
    const float* ea  = (const float*)d_in[3];
    const float* W0l = (const float*)d_in[4];
    const float* b0l = (const float*)d_in[5];
    const float* W0r = (const float*)d_in[6];
    const float* W0e = (const float*)d_in[7];
    const float* a0  = (const float*)d_in[8];
    const float* c0  = (const float*)d_in[9];
    const float* Wl  = (const float*)d_in[10];
    const float* bl  = (const float*)d_in[11];
    const float* Wr  = (const float*)d_in[12];
    const float* We  = (const float*)d_in[13];
    const float* a   = (const float*)d_in[14];
    const float* cb  = (const float*)d_in[15];
    const float* bng = (const float*)d_in[16];
    const float* bnb = (const float*)d_in[17];
    const float* bnm = (const float*)d_in[18];
    const float* bnv = (const float*)d_in[19];
    const float* Wo1 = (const float*)d_in[20];
    const float* bo1 = (const float*)d_in[21];
    const float* Wo2 = (const float*)d_in[22];
    const float* bo2 = (const float*)d_in[23];

    int Nn = in_sizes[2];
    int Ee = in_sizes[1] / 2;
    int Gg = out_size;
    const int* srcv = ei;
    const int* dstv = ei + Ee;

    char* w = (char*)d_ws;
    auto alloc = [&](size_t bytes) {
        char* p = w;
        w += (bytes + 255) & ~(size_t)255;
        return p;
    };
    __half* xlb    = (__half*)alloc((size_t)Nn * 256 * 2);
    __half* xrb    = (__half*)alloc((size_t)Nn * 256 * 2);
    float*  hbuf   = (float*)alloc((size_t)Nn * 64 * 4);
    int*    deg    = (int*)alloc((size_t)Nn * 4);
    int*    rowptr = (int*)alloc((size_t)(Nn + 1) * 4);
    int*    cursor = (int*)alloc((size_t)Nn * 4);
    float4* csr4   = (float4*)alloc((size_t)Ee * 16);
    float*  pooled = (float*)alloc((size_t)Gg * 64 * 4);
    int*    gstart = (int*)alloc((size_t)(Gg + 1) * 4);
    int*    bsum   = (int*)alloc(256 * 4);
    float*  epi    = (float*)alloc(4 * 128 * 4);
    __half* Wp     = (__half*)alloc((size_t)4 * 32768 * 2);

    int nscan = (Nn + SCAN_ELEMS - 1) / SCAN_ELEMS;  // <=256 for Nn<=262144

    // CSR build + weight/epilogue prep + group starts
    hipMemsetAsync(deg, 0, (size_t)Nn * 4, stream);
    count_kernel<<<(Ee + 255) / 256, 256, 0, stream>>>(dstv, deg, Ee);
    scan_phase1<<<nscan, 256, 0, stream>>>(deg, bsum, Nn);
    scan_phase2<<<1, 256, 0, stream>>>(bsum, nscan, rowptr, Nn);
    scan_phase3<<<nscan, 256, 0, stream>>>(deg, bsum, rowptr, cursor, Nn);
    scatter_kernel<<<(Ee + 255) / 256, 256, 0, stream>>>(srcv, dstv, ea, cursor, csr4, Ee);
    bnprep_kernel<<<1, 256, 0, stream>>>(c0, cb, bng, bnb, bnm, bnv, epi);
    wprep_kernel<<<64, 256, 0, stream>>>(W0l, W0r, Wl, Wr, Wp);
    gstart_kernel<<<(Nn + 255) / 256, 256, 0, stream>>>(bat, gstart, Nn, Gg);

    int gatg = 2048;   // persistent: 2048 blocks x 4 waves = 8192 waves
    int gemg = (Nn + 31) / 32;

    // layer 0 (K=9)
    gemm2_mfma_kernel<9><<<gemg, 256, 0, stream>>>(x, Wp, b0l, xlb, xrb, Nn);
    gat_kernel<<<gatg, 256, 0, stream>>>(xlb, xrb, W0e, a0, epi,
                                         rowptr, csr4, hbuf, nullptr, Nn);
    // 3 residual layers (K=64)
    for (int i = 0; i < 3; i++) {
        gemm2_mfma_kernel<64><<<gemg, 256, 0, stream>>>(
            hbuf, Wp + (size_t)(i + 1) * 32768, bl + (size_t)i * 256, xlb, xrb, Nn);
        gat_kernel<<<gatg, 256, 0, stream>>>(
            xlb, xrb, We + (size_t)i * 768, a + (size_t)i * 256, epi + (size_t)(i + 1) * 128,
            rowptr, csr4, hbuf, hbuf, Nn);
    }

    // global mean pool (no atomics; batch sorted) + head
    pool_kernel<<<Gg, 256, 0, stream>>>(hbuf, gstart, pooled, Gg);
    head_kernel<<<Gg, 64, 0, stream>>>(pooled, Wo1, bo1, Wo2, bo2, (float*)d_out, Gg);
}